// Round 1
// 791.671 us; speedup vs baseline: 1.1584x; 1.1584x over previous
//
#include <hip/hip_runtime.h>
#include <math.h>

typedef short short8 __attribute__((ext_vector_type(8)));
typedef float f32x4 __attribute__((ext_vector_type(4)));
typedef unsigned int uint4v __attribute__((ext_vector_type(4)));

// ---------------- workspace layout (float offsets) ----------------
#define WS_DS_ENC 0            // 4096 u32
#define WS_DT     4096         // 65536 f32
#define WS_SUMS   69632        // 1024 f32
#define WS_SS     70656        // 1024 f32
#define WS_YCLS   71680        // 1,048,576 ushort (524288 fl)  [n][256][64] bf16
#define WS_YREG   595968       // 16,777,216 ushort (8388608 fl) [n][256][1024] bf16
#define WS_XT     8984576      // 16,777,216 ushort  [n][32][32][256] bf16
#define WS_ZT     17373184     // 1,048,576 ushort   [n][64][256] bf16
#define WS_WTR    17897472     // 589,824 ushort  [9][8][4][256][8]
#define WS_WTDR   18192384     // 8,192 ushort    [4][256][8]
#define WS_WTC    18196480     // 589,824 ushort
#define WS_WTDC   18491392     // 8,192 ushort
#define WS_PART   18495488     // 10,485,760 f32  [512][64][320] lin_reg partials
#define WS_XSQ    28981248     // 65,536 f32  [n][1024] exact fp32 sum x^2
#define WS_ZSQ    29046784     // 4,096 f32   [n][64]   exact fp32 sum z^2
// end: 29,050,880 floats = 116.2 MB (ws poison is ~1.3 GB)

__device__ __forceinline__ float dsig(float d) {
    return 4.0f / (1.0f + __expf(d)) - 1.0f;   // monotone decreasing
}
__device__ __forceinline__ unsigned fenc(float f) {
    unsigned u = __float_as_uint(f);
    return (u & 0x80000000u) ? ~u : (u | 0x80000000u);
}
__device__ __forceinline__ float fdec(unsigned e) {
    unsigned u = (e & 0x80000000u) ? (e ^ 0x80000000u) : ~e;
    return __uint_as_float(u);
}
__device__ __forceinline__ unsigned short f2bf(float f) {   // RNE
    unsigned u = __float_as_uint(f);
    return (unsigned short)((u + 0x7fffu + ((u >> 16) & 1u)) >> 16);
}
__device__ __forceinline__ float bf2f(unsigned short h) {
    return __uint_as_float(((unsigned)h) << 16);
}
// truncating pack of 8 fp32 -> short8 bf16 (hi-half packing, ~2 VALU per pair)
__device__ __forceinline__ short8 pack8_trunc(const float* f) {
    uint4v u;
#pragma unroll
    for (int i = 0; i < 4; ++i) {
        unsigned lo = __float_as_uint(f[2 * i]) >> 16;
        unsigned hi = __float_as_uint(f[2 * i + 1]) & 0xffff0000u;
        u[i] = lo | hi;
    }
    return __builtin_bit_cast(short8, u);
}

// ---------------------------------------------------------------- init
__global__ void k_init(unsigned* __restrict__ ds_enc, float* __restrict__ sums,
                       float* __restrict__ out_cls, float* __restrict__ out_loc,
                       const float* __restrict__ lin_cls_b, const float* __restrict__ lin_reg_b) {
    int i = blockIdx.x * 256 + threadIdx.x;
    if (i < 4096) ds_enc[i] = 0u;
    if (i < 1024) sums[i] = 0.0f;
    if (i < 5120) out_cls[i] = lin_cls_b[i % 80];
    if (i < 20480) out_loc[i] = lin_reg_b[i % 320];
}

// ---------------------------------------------------------------- transposes (+ exact fp32 sq-sums)
__global__ __launch_bounds__(256) void k_xt(const float* __restrict__ x, unsigned short* __restrict__ xt,
                                            float* __restrict__ xsq) {
    __shared__ float t[64 * 33];
    __shared__ float xr[4][32];
    const int n = blockIdx.x, row = blockIdx.y;
    const int tid = threadIdx.x;
    const int col = tid & 31, g = tid >> 5;
    float sq = 0.f;
    for (int c4 = 0; c4 < 4; ++c4) {
        const int ic0 = c4 * 64;
        __syncthreads();
        {
            int icl = tid >> 2, cg = tid & 3;
            const float* src = &x[((n * 256 + ic0 + icl) * 32 + row) * 32 + cg * 8];
            float4 a = *reinterpret_cast<const float4*>(src);
            float4 b = *reinterpret_cast<const float4*>(src + 4);
            float* d = &t[icl * 33 + cg * 8];
            d[0] = a.x; d[1] = a.y; d[2] = a.z; d[3] = a.w;
            d[4] = b.x; d[5] = b.y; d[6] = b.z; d[7] = b.w;
        }
        __syncthreads();
        {
            short8 v;
#pragma unroll
            for (int j = 0; j < 8; ++j) {
                float f = t[(g * 8 + j) * 33 + col];
                sq = fmaf(f, f, sq);
                v[j] = (short)f2bf(f);
            }
            *reinterpret_cast<short8*>(&xt[((n * 32 + row) * 32 + col) * 256 + ic0 + g * 8]) = v;
        }
    }
    // reduce sq over the 8 g-groups per col (g pairs live in one wave, then LDS)
    sq += __shfl_xor(sq, 32);
    if ((tid & 63) < 32) xr[tid >> 6][col] = sq;
    __syncthreads();
    if (tid < 32) xsq[(n * 32 + row) * 32 + tid] = xr[0][tid] + xr[1][tid] + xr[2][tid] + xr[3][tid];
}

__global__ __launch_bounds__(256) void k_zt(const float* __restrict__ z, unsigned short* __restrict__ zt,
                                            float* __restrict__ zsq) {
    __shared__ float t[64 * 65];
    __shared__ float zr[4][64];
    const int n = blockIdx.x;
    const int tid = threadIdx.x;
    const int pos = tid & 63, gg = tid >> 6;
    float sq = 0.f;
    for (int c4 = 0; c4 < 4; ++c4) {
        const int ic0 = c4 * 64;
        __syncthreads();
        {
            int icl = tid >> 2, pg = tid & 3;
            const float* src = &z[(n * 256 + ic0 + icl) * 64 + pg * 16];
#pragma unroll
            for (int r = 0; r < 4; ++r) {
                float4 a = *reinterpret_cast<const float4*>(src + r * 4);
                float* d = &t[icl * 65 + pg * 16 + r * 4];
                d[0] = a.x; d[1] = a.y; d[2] = a.z; d[3] = a.w;
            }
        }
        __syncthreads();
        {
            short8 v0, v1;
#pragma unroll
            for (int j = 0; j < 8; ++j) {
                float f = t[(gg * 16 + j) * 65 + pos];
                sq = fmaf(f, f, sq);
                v0[j] = (short)f2bf(f);
            }
#pragma unroll
            for (int j = 0; j < 8; ++j) {
                float f = t[(gg * 16 + 8 + j) * 65 + pos];
                sq = fmaf(f, f, sq);
                v1[j] = (short)f2bf(f);
            }
            unsigned short* d = &zt[(n * 64 + pos) * 256 + ic0 + gg * 16];
            *reinterpret_cast<short8*>(d) = v0;
            *reinterpret_cast<short8*>(d + 8) = v1;
        }
    }
    zr[gg][pos] = sq;
    __syncthreads();
    if (tid < 64) zsq[n * 64 + tid] = zr[0][tid] + zr[1][tid] + zr[2][tid] + zr[3][tid];
}

// ---------------------------------------------------------------- weight swizzle
__global__ void k_wswz(const float* __restrict__ wr, const float* __restrict__ wc,
                       unsigned short* __restrict__ wtr, unsigned short* __restrict__ wtdr,
                       unsigned short* __restrict__ wtc, unsigned short* __restrict__ wtdc) {
    const int idx = blockIdx.x * 256 + threadIdx.x;
    const float* src = blockIdx.y ? wc : wr;
    unsigned short* dw = blockIdx.y ? wtc : wtr;
    unsigned short* dd = blockIdx.y ? wtdc : wtdr;
    if (idx < 73728) {
        int tap = idx >> 13, rem = idx & 8191;
        int kc = rem >> 10, rem2 = rem & 1023;
        int q = rem2 >> 8, oc = rem2 & 255;
        short8 v;
#pragma unroll
        for (int j = 0; j < 8; ++j) {
            int icg = 1 + kc * 32 + q * 8 + j;
            v[j] = (short)f2bf(src[(oc * 257 + icg) * 9 + tap]);
        }
        *reinterpret_cast<short8*>(&dw[idx * 8]) = v;
    } else if (idx < 74752) {
        int i2 = idx - 73728;
        int q = i2 >> 8, oc = i2 & 255;
        short8 v;
#pragma unroll
        for (int j = 0; j < 8; ++j) {
            int k = q * 8 + j;
            v[j] = (k < 9) ? (short)f2bf(src[(oc * 257) * 9 + k]) : (short)0;
        }
        *reinterpret_cast<short8*>(&dd[i2 * 8]) = v;
    }
}

// ---------------------------------------------------------------- dist (MFMA)
// d[p][q] = zsq[p] + xsq[q] - 2*(z.x); cross-term via bf16 MFMA on zt/xt, sq-terms exact fp32.
// grid (4, 64): block = 256 q, wave = 64 q x all 64 p. C-frag: p=(lane>>4)*4+e (+16*mi), q=lane&15 (+16*ni).
__global__ __launch_bounds__(256) void k_dist(const unsigned short* __restrict__ zt,
                                              const unsigned short* __restrict__ xt,
                                              const float* __restrict__ zsq, const float* __restrict__ xsq,
                                              float* __restrict__ dist_t, unsigned* __restrict__ ds_enc) {
    const int n = blockIdx.y;
    const int tid = threadIdx.x;
    const int wv = tid >> 6, lane = tid & 63;
    const int l15 = lane & 15, q4 = lane >> 4;
    const int q0 = blockIdx.x * 256 + wv * 64;
    const unsigned short* zb = zt + n * 16384;
    const unsigned short* xb = xt + (size_t)(n * 1024 + q0) * 256;

    f32x4 acc[4][4];
#pragma unroll
    for (int mi = 0; mi < 4; ++mi)
#pragma unroll
        for (int ni = 0; ni < 4; ++ni) acc[mi][ni] = (f32x4){0.f, 0.f, 0.f, 0.f};

#pragma unroll
    for (int ks = 0; ks < 8; ++ks) {
        short8 a[4], b[4];
#pragma unroll
        for (int mi = 0; mi < 4; ++mi)
            a[mi] = *reinterpret_cast<const short8*>(&zb[(mi * 16 + l15) * 256 + ks * 32 + q4 * 8]);
#pragma unroll
        for (int ni = 0; ni < 4; ++ni)
            b[ni] = *reinterpret_cast<const short8*>(&xb[(ni * 16 + l15) * 256 + ks * 32 + q4 * 8]);
#pragma unroll
        for (int ni = 0; ni < 4; ++ni)
#pragma unroll
            for (int mi = 0; mi < 4; ++mi)
                acc[mi][ni] = __builtin_amdgcn_mfma_f32_16x16x32_bf16(a[mi], b[ni], acc[mi][ni], 0, 0, 0);
    }

    float zs[4][4];
#pragma unroll
    for (int mi = 0; mi < 4; ++mi)
#pragma unroll
        for (int e = 0; e < 4; ++e) zs[mi][e] = zsq[n * 64 + mi * 16 + q4 * 4 + e];
    float xq[4];
#pragma unroll
    for (int ni = 0; ni < 4; ++ni) xq[ni] = xsq[n * 1024 + q0 + ni * 16 + l15];

    // dist_t[q] = dsig(max_p d): in-lane max over (mi,e), then reduce across the 4 row-groups.
#pragma unroll
    for (int ni = 0; ni < 4; ++ni) {
        float m = -1e30f;
#pragma unroll
        for (int mi = 0; mi < 4; ++mi)
#pragma unroll
            for (int e = 0; e < 4; ++e)
                m = fmaxf(m, zs[mi][e] - 2.f * acc[mi][ni][e]);
        m = fmaxf(m, __shfl_xor(m, 16));
        m = fmaxf(m, __shfl_xor(m, 32));
        if (lane < 16) dist_t[n * 1024 + q0 + ni * 16 + l15] = dsig(m + xq[ni]);
    }
    // dist_s[p] partial: max over this wave's 64 q, then atomicMax on the raw-d encoding.
#pragma unroll
    for (int mi = 0; mi < 4; ++mi)
#pragma unroll
        for (int e = 0; e < 4; ++e) {
            float v = -1e30f;
#pragma unroll
            for (int ni = 0; ni < 4; ++ni) v = fmaxf(v, xq[ni] - 2.f * acc[mi][ni][e]);
            v = fmaxf(v, __shfl_xor(v, 1));
            v = fmaxf(v, __shfl_xor(v, 2));
            v = fmaxf(v, __shfl_xor(v, 4));
            v = fmaxf(v, __shfl_xor(v, 8));
            if (l15 == 0) atomicMax(&ds_enc[n * 64 + mi * 16 + q4 * 4 + e], fenc(zs[mi][e] + v));
        }
}

// ---------------------------------------------------------------- conv_reg MFMA
__global__ __launch_bounds__(256) void k_conv_reg(
    const unsigned short* __restrict__ xt, const float* __restrict__ dist_t,
    const unsigned short* __restrict__ wt, const unsigned short* __restrict__ wtd,
    unsigned short* __restrict__ y, float* __restrict__ sums) {
    __shared__ __align__(16) char smem[17408];
    unsigned short* As = (unsigned short*)smem;              // 204*40
    unsigned short* Ds = (unsigned short*)(smem + 16320);    // 204
    float* Ts = (float*)smem;                                // 4*1088 after barrier

    const int n = blockIdx.y;
    const int pt = blockIdx.x >> 1, ot = blockIdx.x & 1;
    const int tid = threadIdx.x;
    const int w = tid >> 6, lane = tid & 63;
    const int l15 = lane & 15, q = lane >> 4;
    const int wm = w & 1, wn = w >> 1;
    const int ocW = ot * 128 + wn * 64;

    f32x4 acc[4][4];
#pragma unroll
    for (int mi = 0; mi < 4; ++mi)
#pragma unroll
        for (int ni = 0; ni < 4; ++ni) acc[mi][ni] = (f32x4){0.f, 0.f, 0.f, 0.f};

    for (int f = tid; f < 204; f += 256) {
        int rr = f / 34, cc = f % 34;
        int prow = pt * 4 + rr;
        float v = 0.f;
        if (prow >= 1 && prow <= 32 && cc >= 1 && cc <= 32)
            v = dist_t[n * 1024 + (prow - 1) * 32 + (cc - 1)];
        Ds[f] = f2bf(v);
    }
    __syncthreads();
    {
        short8 ad[4];
#pragma unroll
        for (int mi = 0; mi < 4; ++mi) {
            int m = wm * 64 + mi * 16 + l15;
            int r = m >> 5, c = m & 31;
            short8 v = {0, 0, 0, 0, 0, 0, 0, 0};
#pragma unroll
            for (int j = 0; j < 8; ++j) {
                int k = q * 8 + j;
                if (k < 9) {
                    int ky = k / 3, kx = k % 3;
                    v[j] = (short)Ds[(r + ky) * 34 + (c + kx)];
                }
            }
            ad[mi] = v;
        }
#pragma unroll
        for (int ni = 0; ni < 4; ++ni) {
            short8 b = *reinterpret_cast<const short8*>(&wtd[(q * 256 + ocW + ni * 16 + l15) * 8]);
#pragma unroll
            for (int mi = 0; mi < 4; ++mi)
                acc[mi][ni] = __builtin_amdgcn_mfma_f32_16x16x32_bf16(ad[mi], b, acc[mi][ni], 0, 0, 0);
        }
    }

    for (int kc = 0; kc < 8; ++kc) {
        __syncthreads();
#pragma unroll
        for (int it = 0; it < 4; ++it) {
            int f = tid + 256 * it;
            if (f < 816) {
                int cell = f >> 2, ch = f & 3;
                int rr = cell / 34, cc = cell % 34;
                int prow = pt * 4 + rr;
                short8 v = {0, 0, 0, 0, 0, 0, 0, 0};
                if (prow >= 1 && prow <= 32 && cc >= 1 && cc <= 32)
                    v = *reinterpret_cast<const short8*>(
                        &xt[((n * 32 + prow - 1) * 32 + cc - 1) * 256 + kc * 32 + ch * 8]);
                *reinterpret_cast<short8*>(&As[cell * 40 + ch * 8]) = v;
            }
        }
        __syncthreads();
#pragma unroll
        for (int tap = 0; tap < 9; ++tap) {
            const int ky = tap / 3, kx = tap % 3;
            short8 a[4];
#pragma unroll
            for (int mi = 0; mi < 4; ++mi) {
                int m = wm * 64 + mi * 16 + l15;
                int r = (m >> 5) + ky, c = (m & 31) + kx;
                a[mi] = *reinterpret_cast<const short8*>(&As[(r * 34 + c) * 40 + q * 8]);
            }
            const unsigned short* wb = wt + (size_t)(((tap * 8 + kc) * 4 + q) * 256) * 8;
#pragma unroll
            for (int ni = 0; ni < 4; ++ni) {
                short8 b = *reinterpret_cast<const short8*>(&wb[(ocW + ni * 16 + l15) * 8]);
#pragma unroll
                for (int mi = 0; mi < 4; ++mi)
                    acc[mi][ni] = __builtin_amdgcn_mfma_f32_16x16x32_bf16(a[mi], b, acc[mi][ni], 0, 0, 0);
            }
        }
    }

#pragma unroll
    for (int ni = 0; ni < 4; ++ni) {
        float s = 0.f, qq = 0.f;
#pragma unroll
        for (int mi = 0; mi < 4; ++mi)
#pragma unroll
            for (int e = 0; e < 4; ++e) {
                float v = acc[mi][ni][e];
                s += v; qq = fmaf(v, v, qq);
            }
        s += __shfl_xor(s, 16); s += __shfl_xor(s, 32);
        qq += __shfl_xor(qq, 16); qq += __shfl_xor(qq, 32);
        if (lane < 16) {
            atomicAdd(&sums[512 + ocW + ni * 16 + l15], s);
            atomicAdd(&sums[768 + ocW + ni * 16 + l15], qq);
        }
    }

    __syncthreads();
    float* T = Ts + w * 1088;
#pragma unroll
    for (int mi = 0; mi < 4; ++mi) {
#pragma unroll
        for (int ni = 0; ni < 4; ++ni)
#pragma unroll
            for (int e = 0; e < 4; ++e)
                T[(ni * 16 + l15) * 17 + q * 4 + e] = acc[mi][ni][e];
#pragma unroll
        for (int eo = 0; eo < 16; ++eo) {
            int ocl = eo * 4 + q;
            float v = T[ocl * 17 + l15];
            y[(size_t)n * 262144 + (size_t)(ocW + ocl) * 1024 + pt * 128 + wm * 64 + mi * 16 + l15] = f2bf(v);
        }
    }
}

// ---------------------------------------------------------------- conv_cls MFMA
__global__ __launch_bounds__(256) void k_conv_cls(
    const unsigned short* __restrict__ zt, const unsigned* __restrict__ ds_enc,
    const unsigned short* __restrict__ wt, const unsigned short* __restrict__ wtd,
    unsigned short* __restrict__ y, float* __restrict__ sums) {
    __shared__ __align__(16) char smem[17408];
    unsigned short* As = (unsigned short*)smem;
    unsigned short* Ds = (unsigned short*)(smem + 16000);
    float* Ts = (float*)smem;

    const int n0 = blockIdx.x * 2;
    const int ob = blockIdx.y;
    const int tid = threadIdx.x;
    const int w = tid >> 6, lane = tid & 63;
    const int l15 = lane & 15, q = lane >> 4;
    const int wm = w & 1, wn = w >> 1;
    const int ocW = ob * 128 + wn * 64;

    f32x4 acc[4][4];
#pragma unroll
    for (int mi = 0; mi < 4; ++mi)
#pragma unroll
        for (int ni = 0; ni < 4; ++ni) acc[mi][ni] = (f32x4){0.f, 0.f, 0.f, 0.f};

    for (int f = tid; f < 200; f += 256) {
        int n_l = f / 100, rem = f % 100;
        int rr = rem / 10, cc = rem % 10;
        float v = 0.f;
        if (rr >= 1 && rr <= 8 && cc >= 1 && cc <= 8)
            v = dsig(fdec(ds_enc[(n0 + n_l) * 64 + (rr - 1) * 8 + (cc - 1)]));
        Ds[f] = f2bf(v);
    }
    __syncthreads();
    {
        short8 ad[4];
#pragma unroll
        for (int mi = 0; mi < 4; ++mi) {
            int pos = mi * 16 + l15;
            int r = pos >> 3, c = pos & 7;
            short8 v = {0, 0, 0, 0, 0, 0, 0, 0};
#pragma unroll
            for (int j = 0; j < 8; ++j) {
                int k = q * 8 + j;
                if (k < 9) {
                    int ky = k / 3, kx = k % 3;
                    v[j] = (short)Ds[wm * 100 + (r + ky) * 10 + (c + kx)];
                }
            }
            ad[mi] = v;
        }
#pragma unroll
        for (int ni = 0; ni < 4; ++ni) {
            short8 b = *reinterpret_cast<const short8*>(&wtd[(q * 256 + ocW + ni * 16 + l15) * 8]);
#pragma unroll
            for (int mi = 0; mi < 4; ++mi)
                acc[mi][ni] = __builtin_amdgcn_mfma_f32_16x16x32_bf16(ad[mi], b, acc[mi][ni], 0, 0, 0);
        }
    }

    for (int kc = 0; kc < 8; ++kc) {
        __syncthreads();
#pragma unroll
        for (int it = 0; it < 4; ++it) {
            int f = tid + 256 * it;
            if (f < 800) {
                int cell = f >> 2, ch = f & 3;
                int n_l = cell / 100, rem = cell % 100;
                int rr = rem / 10, cc = rem % 10;
                short8 v = {0, 0, 0, 0, 0, 0, 0, 0};
                if (rr >= 1 && rr <= 8 && cc >= 1 && cc <= 8)
                    v = *reinterpret_cast<const short8*>(
                        &zt[((n0 + n_l) * 64 + (rr - 1) * 8 + (cc - 1)) * 256 + kc * 32 + ch * 8]);
                *reinterpret_cast<short8*>(&As[cell * 40 + ch * 8]) = v;
            }
        }
        __syncthreads();
#pragma unroll
        for (int tap = 0; tap < 9; ++tap) {
            const int ky = tap / 3, kx = tap % 3;
            short8 a[4];
#pragma unroll
            for (int mi = 0; mi < 4; ++mi) {
                int pos = mi * 16 + l15;
                int r = (pos >> 3) + ky, c = (pos & 7) + kx;
                a[mi] = *reinterpret_cast<const short8*>(&As[(wm * 100 + r * 10 + c) * 40 + q * 8]);
            }
            const unsigned short* wb = wt + (size_t)(((tap * 8 + kc) * 4 + q) * 256) * 8;
#pragma unroll
            for (int ni = 0; ni < 4; ++ni) {
                short8 b = *reinterpret_cast<const short8*>(&wb[(ocW + ni * 16 + l15) * 8]);
#pragma unroll
                for (int mi = 0; mi < 4; ++mi)
                    acc[mi][ni] = __builtin_amdgcn_mfma_f32_16x16x32_bf16(a[mi], b, acc[mi][ni], 0, 0, 0);
            }
        }
    }

#pragma unroll
    for (int ni = 0; ni < 4; ++ni) {
        float s = 0.f, qq = 0.f;
#pragma unroll
        for (int mi = 0; mi < 4; ++mi)
#pragma unroll
            for (int e = 0; e < 4; ++e) {
                float v = acc[mi][ni][e];
                s += v; qq = fmaf(v, v, qq);
            }
        s += __shfl_xor(s, 16); s += __shfl_xor(s, 32);
        qq += __shfl_xor(qq, 16); qq += __shfl_xor(qq, 32);
        if (lane < 16) {
            atomicAdd(&sums[0 + ocW + ni * 16 + l15], s);
            atomicAdd(&sums[256 + ocW + ni * 16 + l15], qq);
        }
    }

    __syncthreads();
    float* T = Ts + w * 1088;
#pragma unroll
    for (int mi = 0; mi < 4; ++mi) {
#pragma unroll
        for (int ni = 0; ni < 4; ++ni)
#pragma unroll
            for (int e = 0; e < 4; ++e)
                T[(ni * 16 + l15) * 17 + q * 4 + e] = acc[mi][ni][e];
#pragma unroll
        for (int eo = 0; eo < 16; ++eo) {
            int ocl = eo * 4 + q;
            float v = T[ocl * 17 + l15];
            y[(size_t)(n0 + wm) * 16384 + (size_t)(ocW + ocl) * 64 + mi * 16 + l15] = f2bf(v);
        }
    }
}

// ---------------------------------------------------------------- BN finalize
__global__ void k_bnfin(const float* __restrict__ sums,
                        const float* __restrict__ g_cls, const float* __restrict__ b_cls,
                        const float* __restrict__ g_reg, const float* __restrict__ b_reg,
                        float* __restrict__ ss) {
    int t = threadIdx.x;
    {
        float mean = sums[t] * (1.f / 4096.f);
        float var = sums[256 + t] * (1.f / 4096.f) - mean * mean;
        float sc = g_cls[t] * rsqrtf(var + 1e-5f);
        ss[t] = sc;
        ss[256 + t] = b_cls[t] - mean * sc;
    }
    {
        float mean = sums[512 + t] * (1.f / 65536.f);
        float var = sums[768 + t] * (1.f / 65536.f) - mean * mean;
        float sc = g_reg[t] * rsqrtf(var + 1e-5f);
        ss[512 + t] = sc;
        ss[768 + t] = b_reg[t] - mean * sc;
    }
}

// ---------------------------------------------------------------- lin_cls MFMA (K-split, W read once)
// grid 64 blocks (K-chunk 256 each), 4 waves: wave wv owns n-rows [16wv,16wv+16), all 80 j.
// A = relu(bn(y_cls)) packed bf16; B = lin_cls_w fp32 -> bf16 trunc. atomicAdd into bias-seeded out.
__global__ __launch_bounds__(256) void k_lin_cls(const unsigned short* __restrict__ y, const float* __restrict__ ss,
                                                 const float* __restrict__ w, float* __restrict__ out) {
    const int kb = blockIdx.x * 256;
    const int tid = threadIdx.x;
    const int wv = tid >> 6, lane = tid & 63;
    const int l15 = lane & 15, q4 = lane >> 4;
    f32x4 acc[5];
#pragma unroll
    for (int ni = 0; ni < 5; ++ni) acc[ni] = (f32x4){0.f, 0.f, 0.f, 0.f};
#pragma unroll
    for (int ks = 0; ks < 8; ++ks) {
        const int k0 = kb + ks * 32 + q4 * 8;
        short8 yv = *reinterpret_cast<const short8*>(&y[(wv * 16 + l15) * 16384 + k0]);
        const int ch = k0 >> 6;
        const float sc = ss[ch], sh = ss[256 + ch];
        float f[8];
#pragma unroll
        for (int j = 0; j < 8; ++j) f[j] = fmaxf(fmaf(bf2f((unsigned short)yv[j]), sc, sh), 0.f);
        short8 a = pack8_trunc(f);
#pragma unroll
        for (int ni = 0; ni < 5; ++ni) {
            const float* wp = &w[(size_t)(ni * 16 + l15) * 16384 + k0];
            float4 b0 = *reinterpret_cast<const float4*>(wp);
            float4 b1 = *reinterpret_cast<const float4*>(wp + 4);
            float g[8] = {b0.x, b0.y, b0.z, b0.w, b1.x, b1.y, b1.z, b1.w};
            acc[ni] = __builtin_amdgcn_mfma_f32_16x16x32_bf16(a, pack8_trunc(g), acc[ni], 0, 0, 0);
        }
    }
#pragma unroll
    for (int ni = 0; ni < 5; ++ni)
#pragma unroll
        for (int e = 0; e < 4; ++e)
            atomicAdd(&out[(wv * 16 + q4 * 4 + e) * 80 + ni * 16 + l15], acc[ni][e]);
}

// ---------------------------------------------------------------- lin_reg MFMA (streaming W)
__global__ __launch_bounds__(256) void k_lin_reg2(const unsigned short* __restrict__ y, const float* __restrict__ ss,
                                                  const float* __restrict__ w, float* __restrict__ part) {
    __shared__ __align__(16) unsigned short A_l[32 * 520];   // 32 regions x (64n x 8 bf16 + 8 pad)
    const int k0 = blockIdx.x * 512;
    const int tid = threadIdx.x;
    const int wv = tid >> 6, lane = tid & 63;
    const int l15 = lane & 15, q = lane >> 4;
    const int jw = wv * 80;

    f32x4 acc[5][4];
#pragma unroll
    for (int ni = 0; ni < 5; ++ni)
#pragma unroll
        for (int mi = 0; mi < 4; ++mi) acc[ni][mi] = (f32x4){0.f, 0.f, 0.f, 0.f};

    for (int scn = 0; scn < 2; ++scn) {
        const int ksub = k0 + scn * 256;
        const int ch = ksub >> 10;
        const float scf = ss[512 + ch], shf = ss[768 + ch];
        __syncthreads();
        {
            const int c = tid & 31, nb = tid >> 5;
#pragma unroll
            for (int p = 0; p < 8; ++p) {
                const int n = p * 8 + nb;
                short8 v = *reinterpret_cast<const short8*>(&y[(size_t)n * 262144 + ksub + c * 8]);
                float f[8];
#pragma unroll
                for (int j = 0; j < 8; ++j)
                    f[j] = fmaxf(fmaf(bf2f((unsigned short)v[j]), scf, shf), 0.f);
                *reinterpret_cast<short8*>(&A_l[c * 520 + n * 8]) = pack8_trunc(f);
            }
        }
        __syncthreads();
#pragma unroll
        for (int kk = 0; kk < 8; ++kk) {
            short8 a[4];
#pragma unroll
            for (int mi = 0; mi < 4; ++mi)
                a[mi] = *reinterpret_cast<const short8*>(&A_l[(kk * 4 + q) * 520 + (mi * 16 + l15) * 8]);
            short8 b[5];
#pragma unroll
            for (int ni = 0; ni < 5; ++ni) {
                const float* wp = &w[(size_t)(jw + ni * 16 + l15) * 262144 + ksub + kk * 32 + q * 8];
                float4 b0 = *reinterpret_cast<const float4*>(wp);
                float4 b1 = *reinterpret_cast<const float4*>(wp + 4);
                float f[8] = {b0.x, b0.y, b0.z, b0.w, b1.x, b1.y, b1.z, b1.w};
                b[ni] = pack8_trunc(f);
            }
#pragma unroll
            for (int ni = 0; ni < 5; ++ni)
#pragma unroll
                for (int mi = 0; mi < 4; ++mi)
                    acc[ni][mi] = __builtin_amdgcn_mfma_f32_16x16x32_bf16(a[mi], b[ni], acc[ni][mi], 0, 0, 0);
        }
    }

    float* pb = part + (size_t)blockIdx.x * 20480;
#pragma unroll
    for (int ni = 0; ni < 5; ++ni) {
        const int j = jw + ni * 16 + l15;
#pragma unroll
        for (int mi = 0; mi < 4; ++mi)
#pragma unroll
            for (int e = 0; e < 4; ++e) {
                const int n = mi * 16 + q * 4 + e;
                pb[n * 320 + j] = acc[ni][mi][e];
            }
    }
}

// reduce: out[n][j] (+= bias, pre-seeded) over 512 partial blocks; grid (80, 4)
__global__ __launch_bounds__(256) void k_lin_red(const float* __restrict__ part, float* __restrict__ out_loc) {
    const int idx = blockIdx.x * 256 + threadIdx.x;       // 0..20479
    const int b0 = blockIdx.y * 128;
    float s0 = 0.f, s1 = 0.f, s2 = 0.f, s3 = 0.f;
#pragma unroll 4
    for (int b = 0; b < 128; b += 4) {
        s0 += part[(size_t)(b0 + b + 0) * 20480 + idx];
        s1 += part[(size_t)(b0 + b + 1) * 20480 + idx];
        s2 += part[(size_t)(b0 + b + 2) * 20480 + idx];
        s3 += part[(size_t)(b0 + b + 3) * 20480 + idx];
    }
    atomicAdd(&out_loc[idx], (s0 + s1) + (s2 + s3));
}

// ---------------------------------------------------------------- launch
extern "C" void kernel_launch(void* const* d_in, const int* in_sizes, int n_in,
                              void* d_out, int out_size, void* d_ws, size_t ws_size,
                              hipStream_t stream) {
    const float* z_f        = (const float*)d_in[0];
    const float* x_f        = (const float*)d_in[1];
    const float* conv_cls_w = (const float*)d_in[2];
    const float* bn_cls_g   = (const float*)d_in[3];
    const float* bn_cls_b   = (const float*)d_in[4];
    const float* conv_reg_w = (const float*)d_in[5];
    const float* bn_reg_g   = (const float*)d_in[6];
    const float* bn_reg_b   = (const float*)d_in[7];
    const float* lin_cls_w  = (const float*)d_in[8];
    const float* lin_cls_b  = (const float*)d_in[9];
    const float* lin_reg_w  = (const float*)d_in[10];
    const float* lin_reg_b  = (const float*)d_in[11];

    float* out = (float*)d_out;
    float* ws  = (float*)d_ws;
    unsigned* ds_enc = (unsigned*)(ws + WS_DS_ENC);
    float* dist_t = ws + WS_DT;
    float* sums   = ws + WS_SUMS;
    float* ss     = ws + WS_SS;
    unsigned short* y_cls = (unsigned short*)(ws + WS_YCLS);
    unsigned short* y_reg = (unsigned short*)(ws + WS_YREG);
    unsigned short* xt    = (unsigned short*)(ws + WS_XT);
    unsigned short* zt    = (unsigned short*)(ws + WS_ZT);
    unsigned short* wtr   = (unsigned short*)(ws + WS_WTR);
    unsigned short* wtdr  = (unsigned short*)(ws + WS_WTDR);
    unsigned short* wtc   = (unsigned short*)(ws + WS_WTC);
    unsigned short* wtdc  = (unsigned short*)(ws + WS_WTDC);
    float* part   = ws + WS_PART;
    float* xsq    = ws + WS_XSQ;
    float* zsq    = ws + WS_ZSQ;

    hipLaunchKernelGGL(k_init, dim3(80), dim3(256), 0, stream, ds_enc, sums, out, out + 5120, lin_cls_b, lin_reg_b);
    hipLaunchKernelGGL(k_xt, dim3(64, 32), dim3(256), 0, stream, x_f, xt, xsq);
    hipLaunchKernelGGL(k_zt, dim3(64), dim3(256), 0, stream, z_f, zt, zsq);
    hipLaunchKernelGGL(k_wswz, dim3(292, 2), dim3(256), 0, stream, conv_reg_w, conv_cls_w, wtr, wtdr, wtc, wtdc);
    hipLaunchKernelGGL(k_dist, dim3(4, 64), dim3(256), 0, stream, zt, xt, zsq, xsq, dist_t, ds_enc);
    hipLaunchKernelGGL(k_conv_reg, dim3(16, 64), dim3(256), 0, stream, xt, dist_t, wtr, wtdr, y_reg, sums);
    hipLaunchKernelGGL(k_conv_cls, dim3(32, 2), dim3(256), 0, stream, zt, ds_enc, wtc, wtdc, y_cls, sums);
    hipLaunchKernelGGL(k_bnfin, dim3(1), dim3(256), 0, stream, sums, bn_cls_g, bn_cls_b, bn_reg_g, bn_reg_b, ss);
    hipLaunchKernelGGL(k_lin_cls, dim3(64), dim3(256), 0, stream, y_cls, ss, lin_cls_w, out);
    hipLaunchKernelGGL(k_lin_reg2, dim3(512), dim3(256), 0, stream, y_reg, ss, lin_reg_w, part);
    hipLaunchKernelGGL(k_lin_red, dim3(80, 4), dim3(256), 0, stream, part, out + 5120);
}

// Round 2
// 761.462 us; speedup vs baseline: 1.2044x; 1.0397x over previous
//
#include <hip/hip_runtime.h>
#include <math.h>

typedef short short8 __attribute__((ext_vector_type(8)));
typedef float f32x4 __attribute__((ext_vector_type(4)));
typedef unsigned int uint4v __attribute__((ext_vector_type(4)));

// ---------------- workspace layout (float offsets) ----------------
#define WS_DS_ENC 0            // 4096 u32
#define WS_DT     4096         // 65536 f32
#define WS_SUMS   69632        // 1024 f32
#define WS_SS     70656        // 1024 f32 (unused now; bnfin folded into consumers)
#define WS_YCLS   71680        // 1,048,576 ushort (524288 fl)  [n][256][64] bf16
#define WS_YREG   595968       // 16,777,216 ushort (8388608 fl) [n][256][1024] bf16
#define WS_XT     8984576      // 16,777,216 ushort  [n][32][32][256] bf16
#define WS_ZT     17373184     // 1,048,576 ushort   [n][64][256] bf16
#define WS_WTR    17897472     // 589,824 ushort  [9][8][4][256][8]
#define WS_WTDR   18192384     // 8,192 ushort    [4][256][8]
#define WS_WTC    18196480     // 589,824 ushort
#define WS_WTDC   18491392     // 8,192 ushort
#define WS_PART   18495488     // 10,485,760 f32  [512][64][320] lin_reg partials
#define WS_XSQ    28981248     // 65,536 f32  [n][1024] exact fp32 sum x^2
#define WS_ZSQ    29046784     // 4,096 f32   [n][64]   exact fp32 sum z^2

__device__ __forceinline__ float dsig(float d) {
    return 4.0f / (1.0f + __expf(d)) - 1.0f;   // monotone decreasing
}
__device__ __forceinline__ unsigned fenc(float f) {
    unsigned u = __float_as_uint(f);
    return (u & 0x80000000u) ? ~u : (u | 0x80000000u);
}
__device__ __forceinline__ float fdec(unsigned e) {
    unsigned u = (e & 0x80000000u) ? (e ^ 0x80000000u) : ~e;
    return __uint_as_float(u);
}
__device__ __forceinline__ unsigned short f2bf(float f) {   // RNE
    unsigned u = __float_as_uint(f);
    return (unsigned short)((u + 0x7fffu + ((u >> 16) & 1u)) >> 16);
}
__device__ __forceinline__ float bf2f(unsigned short h) {
    return __uint_as_float(((unsigned)h) << 16);
}
__device__ __forceinline__ short8 pack8_trunc(const float* f) {
    uint4v u;
#pragma unroll
    for (int i = 0; i < 4; ++i) {
        unsigned lo = __float_as_uint(f[2 * i]) >> 16;
        unsigned hi = __float_as_uint(f[2 * i + 1]) & 0xffff0000u;
        u[i] = lo | hi;
    }
    return __builtin_bit_cast(short8, u);
}
// raw barrier: LDS writes visible, but prefetch global loads stay in flight (no vmcnt drain)
__device__ __forceinline__ void barrier_lgkm() {
    asm volatile("s_waitcnt lgkmcnt(0)" ::: "memory");
    __builtin_amdgcn_s_barrier();
    __builtin_amdgcn_sched_barrier(0);
}

// ---------------------------------------------------------------- prep: xt + zt + wswz + init (merged)
__global__ __launch_bounds__(256) void k_prep(
    const float* __restrict__ x, const float* __restrict__ z,
    const float* __restrict__ wr, const float* __restrict__ wc,
    unsigned short* __restrict__ xt, unsigned short* __restrict__ zt,
    float* __restrict__ xsq, float* __restrict__ zsq,
    unsigned short* __restrict__ wtr, unsigned short* __restrict__ wtdr,
    unsigned short* __restrict__ wtc, unsigned short* __restrict__ wtdc,
    unsigned* __restrict__ ds_enc, float* __restrict__ sums,
    float* __restrict__ out_cls, float* __restrict__ out_loc,
    const float* __restrict__ lin_cls_b, const float* __restrict__ lin_reg_b) {
    __shared__ __align__(16) char pmem[17920];
    const int b = blockIdx.x;
    const int tid = threadIdx.x;
    if (b < 2048) {                       // ---- xt transpose + xsq
        float* t = (float*)pmem;                   // 64*33
        float* xr = (float*)(pmem + 8448);         // 4*32
        const int n = b >> 5, row = b & 31;
        const int col = tid & 31, g = tid >> 5;
        float sq = 0.f;
        for (int c4 = 0; c4 < 4; ++c4) {
            const int ic0 = c4 * 64;
            __syncthreads();
            {
                int icl = tid >> 2, cg = tid & 3;
                const float* src = &x[((n * 256 + ic0 + icl) * 32 + row) * 32 + cg * 8];
                float4 a = *reinterpret_cast<const float4*>(src);
                float4 bb = *reinterpret_cast<const float4*>(src + 4);
                float* d = &t[icl * 33 + cg * 8];
                d[0] = a.x; d[1] = a.y; d[2] = a.z; d[3] = a.w;
                d[4] = bb.x; d[5] = bb.y; d[6] = bb.z; d[7] = bb.w;
            }
            __syncthreads();
            {
                short8 v;
#pragma unroll
                for (int j = 0; j < 8; ++j) {
                    float f = t[(g * 8 + j) * 33 + col];
                    sq = fmaf(f, f, sq);
                    v[j] = (short)f2bf(f);
                }
                *reinterpret_cast<short8*>(&xt[((n * 32 + row) * 32 + col) * 256 + ic0 + g * 8]) = v;
            }
        }
        sq += __shfl_xor(sq, 32);
        if ((tid & 63) < 32) xr[(tid >> 6) * 32 + col] = sq;
        __syncthreads();
        if (tid < 32) xsq[(n * 32 + row) * 32 + tid] = xr[tid] + xr[32 + tid] + xr[64 + tid] + xr[96 + tid];
    } else if (b < 2112) {                // ---- zt transpose + zsq
        float* t = (float*)pmem;                   // 64*65
        float* zr = (float*)(pmem + 16640);        // 4*64
        const int n = b - 2048;
        const int pos = tid & 63, gg = tid >> 6;
        float sq = 0.f;
        for (int c4 = 0; c4 < 4; ++c4) {
            const int ic0 = c4 * 64;
            __syncthreads();
            {
                int icl = tid >> 2, pg = tid & 3;
                const float* src = &z[(n * 256 + ic0 + icl) * 64 + pg * 16];
#pragma unroll
                for (int r = 0; r < 4; ++r) {
                    float4 a = *reinterpret_cast<const float4*>(src + r * 4);
                    float* d = &t[icl * 65 + pg * 16 + r * 4];
                    d[0] = a.x; d[1] = a.y; d[2] = a.z; d[3] = a.w;
                }
            }
            __syncthreads();
            {
                short8 v0, v1;
#pragma unroll
                for (int j = 0; j < 8; ++j) {
                    float f = t[(gg * 16 + j) * 65 + pos];
                    sq = fmaf(f, f, sq);
                    v0[j] = (short)f2bf(f);
                }
#pragma unroll
                for (int j = 0; j < 8; ++j) {
                    float f = t[(gg * 16 + 8 + j) * 65 + pos];
                    sq = fmaf(f, f, sq);
                    v1[j] = (short)f2bf(f);
                }
                unsigned short* d = &zt[(n * 64 + pos) * 256 + ic0 + gg * 16];
                *reinterpret_cast<short8*>(d) = v0;
                *reinterpret_cast<short8*>(d + 8) = v1;
            }
        }
        zr[gg * 64 + pos] = sq;
        __syncthreads();
        if (tid < 64) zsq[n * 64 + tid] = zr[tid] + zr[64 + tid] + zr[128 + tid] + zr[192 + tid];
    } else if (b < 2696) {                // ---- weight swizzle
        const int sub = b - 2112;
        const int by = sub / 292, bx = sub % 292;
        const int idx = bx * 256 + tid;
        const float* src = by ? wc : wr;
        unsigned short* dw = by ? wtc : wtr;
        unsigned short* dd = by ? wtdc : wtdr;
        if (idx < 73728) {
            int tap = idx >> 13, rem = idx & 8191;
            int kc = rem >> 10, rem2 = rem & 1023;
            int q = rem2 >> 8, oc = rem2 & 255;
            short8 v;
#pragma unroll
            for (int j = 0; j < 8; ++j) {
                int icg = 1 + kc * 32 + q * 8 + j;
                v[j] = (short)f2bf(src[(oc * 257 + icg) * 9 + tap]);
            }
            *reinterpret_cast<short8*>(&dw[idx * 8]) = v;
        } else if (idx < 74752) {
            int i2 = idx - 73728;
            int q = i2 >> 8, oc = i2 & 255;
            short8 v;
#pragma unroll
            for (int j = 0; j < 8; ++j) {
                int k = q * 8 + j;
                v[j] = (k < 9) ? (short)f2bf(src[(oc * 257) * 9 + k]) : (short)0;
            }
            *reinterpret_cast<short8*>(&dd[i2 * 8]) = v;
        }
    } else {                              // ---- init
        const int i = (b - 2696) * 256 + tid;
        if (i < 4096) ds_enc[i] = 0u;
        if (i < 1024) sums[i] = 0.0f;
        if (i < 5120) out_cls[i] = lin_cls_b[i % 80];
        if (i < 20480) out_loc[i] = lin_reg_b[i % 320];
    }
}

// ---------------------------------------------------------------- dist (MFMA)
__global__ __launch_bounds__(256) void k_dist(const unsigned short* __restrict__ zt,
                                              const unsigned short* __restrict__ xt,
                                              const float* __restrict__ zsq, const float* __restrict__ xsq,
                                              float* __restrict__ dist_t, unsigned* __restrict__ ds_enc) {
    const int n = blockIdx.y;
    const int tid = threadIdx.x;
    const int wv = tid >> 6, lane = tid & 63;
    const int l15 = lane & 15, q4 = lane >> 4;
    const int q0 = blockIdx.x * 256 + wv * 64;
    const unsigned short* zb = zt + n * 16384;
    const unsigned short* xb = xt + (size_t)(n * 1024 + q0) * 256;

    f32x4 acc[4][4];
#pragma unroll
    for (int mi = 0; mi < 4; ++mi)
#pragma unroll
        for (int ni = 0; ni < 4; ++ni) acc[mi][ni] = (f32x4){0.f, 0.f, 0.f, 0.f};

#pragma unroll
    for (int ks = 0; ks < 8; ++ks) {
        short8 a[4], b[4];
#pragma unroll
        for (int mi = 0; mi < 4; ++mi)
            a[mi] = *reinterpret_cast<const short8*>(&zb[(mi * 16 + l15) * 256 + ks * 32 + q4 * 8]);
#pragma unroll
        for (int ni = 0; ni < 4; ++ni)
            b[ni] = *reinterpret_cast<const short8*>(&xb[(ni * 16 + l15) * 256 + ks * 32 + q4 * 8]);
#pragma unroll
        for (int ni = 0; ni < 4; ++ni)
#pragma unroll
            for (int mi = 0; mi < 4; ++mi)
                acc[mi][ni] = __builtin_amdgcn_mfma_f32_16x16x32_bf16(a[mi], b[ni], acc[mi][ni], 0, 0, 0);
    }

    float zs[4][4];
#pragma unroll
    for (int mi = 0; mi < 4; ++mi)
#pragma unroll
        for (int e = 0; e < 4; ++e) zs[mi][e] = zsq[n * 64 + mi * 16 + q4 * 4 + e];
    float xq[4];
#pragma unroll
    for (int ni = 0; ni < 4; ++ni) xq[ni] = xsq[n * 1024 + q0 + ni * 16 + l15];

#pragma unroll
    for (int ni = 0; ni < 4; ++ni) {
        float m = -1e30f;
#pragma unroll
        for (int mi = 0; mi < 4; ++mi)
#pragma unroll
            for (int e = 0; e < 4; ++e)
                m = fmaxf(m, zs[mi][e] - 2.f * acc[mi][ni][e]);
        m = fmaxf(m, __shfl_xor(m, 16));
        m = fmaxf(m, __shfl_xor(m, 32));
        if (lane < 16) dist_t[n * 1024 + q0 + ni * 16 + l15] = dsig(m + xq[ni]);
    }
#pragma unroll
    for (int mi = 0; mi < 4; ++mi)
#pragma unroll
        for (int e = 0; e < 4; ++e) {
            float v = -1e30f;
#pragma unroll
            for (int ni = 0; ni < 4; ++ni) v = fmaxf(v, xq[ni] - 2.f * acc[mi][ni][e]);
            v = fmaxf(v, __shfl_xor(v, 1));
            v = fmaxf(v, __shfl_xor(v, 2));
            v = fmaxf(v, __shfl_xor(v, 4));
            v = fmaxf(v, __shfl_xor(v, 8));
            if (l15 == 0) atomicMax(&ds_enc[n * 64 + mi * 16 + q4 * 4 + e], fenc(zs[mi][e] + v));
        }
}

// ---------------------------------------------------------------- conv (reg + cls merged, 2-phase prefetch dbuf)
__global__ __launch_bounds__(256) void k_conv(
    const unsigned short* __restrict__ xt, const float* __restrict__ dist_t,
    const unsigned short* __restrict__ zt, const unsigned* __restrict__ ds_enc,
    const unsigned short* __restrict__ wtr, const unsigned short* __restrict__ wtdr,
    const unsigned short* __restrict__ wtc, const unsigned short* __restrict__ wtdc,
    unsigned short* __restrict__ y_reg, unsigned short* __restrict__ y_cls,
    float* __restrict__ sums) {
    __shared__ __align__(16) char smem[33056];
    unsigned short* As0 = (unsigned short*)smem;             // 16320 B
    unsigned short* As1 = (unsigned short*)(smem + 16320);   // 16320 B
    unsigned short* Ds = (unsigned short*)(smem + 32640);    // 408 B
    float* Ts = (float*)smem;

    const int tid = threadIdx.x;
    const int w = tid >> 6, lane = tid & 63;
    const int l15 = lane & 15, q = lane >> 4;
    const int wm = w & 1, wn = w >> 1;

    f32x4 acc[4][4];
#pragma unroll
    for (int mi = 0; mi < 4; ++mi)
#pragma unroll
        for (int ni = 0; ni < 4; ++ni) acc[mi][ni] = (f32x4){0.f, 0.f, 0.f, 0.f};

    if (blockIdx.x < 1024) {
        // ================= conv_reg =================
        const int n = blockIdx.x >> 4, bx = blockIdx.x & 15;
        const int pt = bx >> 1, ot = bx & 1;
        const int ocW = ot * 128 + wn * 64;

        for (int f = tid; f < 204; f += 256) {
            int rr = f / 34, cc = f % 34;
            int prow = pt * 4 + rr;
            float v = 0.f;
            if (prow >= 1 && prow <= 32 && cc >= 1 && cc <= 32)
                v = dist_t[n * 1024 + (prow - 1) * 32 + (cc - 1)];
            Ds[f] = f2bf(v);
        }
        __syncthreads();
        {
            short8 ad[4];
#pragma unroll
            for (int mi = 0; mi < 4; ++mi) {
                int m = wm * 64 + mi * 16 + l15;
                int r = m >> 5, c = m & 31;
                short8 v = {0, 0, 0, 0, 0, 0, 0, 0};
#pragma unroll
                for (int j = 0; j < 8; ++j) {
                    int k = q * 8 + j;
                    if (k < 9) {
                        int ky = k / 3, kx = k % 3;
                        v[j] = (short)Ds[(r + ky) * 34 + (c + kx)];
                    }
                }
                ad[mi] = v;
            }
#pragma unroll
            for (int ni = 0; ni < 4; ++ni) {
                short8 bfr = *reinterpret_cast<const short8*>(&wtdr[(q * 256 + ocW + ni * 16 + l15) * 8]);
#pragma unroll
                for (int mi = 0; mi < 4; ++mi)
                    acc[mi][ni] = __builtin_amdgcn_mfma_f32_16x16x32_bf16(ad[mi], bfr, acc[mi][ni], 0, 0, 0);
            }
        }

        // per-thread staging geometry (4 items)
        int ldso[4]; size_t go[4]; bool gv[4], wvld[4];
#pragma unroll
        for (int it = 0; it < 4; ++it) {
            int f = tid + 256 * it;
            int cell = f >> 2, chn = f & 3;
            int rr = cell / 34, cc = cell % 34;
            int prow = pt * 4 + rr;
            wvld[it] = (f < 816);
            gv[it] = wvld[it] && prow >= 1 && prow <= 32 && cc >= 1 && cc <= 32;
            go[it] = ((size_t)(n * 32 + prow - 1) * 32 + (cc - 1)) * 256 + chn * 8;
            ldso[it] = cell * 40 + chn * 8;
        }
        short8 st[4];
#pragma unroll
        for (int it = 0; it < 4; ++it) {
            short8 v = {0, 0, 0, 0, 0, 0, 0, 0};
            if (gv[it]) v = *reinterpret_cast<const short8*>(&xt[go[it]]);
            st[it] = v;
        }
        for (int kc = 0; kc < 8; ++kc) {
            unsigned short* As = (kc & 1) ? As1 : As0;
#pragma unroll
            for (int it = 0; it < 4; ++it)
                if (wvld[it]) *reinterpret_cast<short8*>(&As[ldso[it]]) = st[it];
            if (kc < 7) {
#pragma unroll
                for (int it = 0; it < 4; ++it) {
                    short8 v = {0, 0, 0, 0, 0, 0, 0, 0};
                    if (gv[it]) v = *reinterpret_cast<const short8*>(&xt[go[it] + (kc + 1) * 32]);
                    st[it] = v;
                }
            }
            barrier_lgkm();
#pragma unroll
            for (int tap = 0; tap < 9; ++tap) {
                const int ky = tap / 3, kx = tap % 3;
                short8 a[4];
#pragma unroll
                for (int mi = 0; mi < 4; ++mi) {
                    int m = wm * 64 + mi * 16 + l15;
                    int r = (m >> 5) + ky, c = (m & 31) + kx;
                    a[mi] = *reinterpret_cast<const short8*>(&As[(r * 34 + c) * 40 + q * 8]);
                }
                const unsigned short* wb = wtr + (size_t)(((tap * 8 + kc) * 4 + q) * 256) * 8;
#pragma unroll
                for (int ni = 0; ni < 4; ++ni) {
                    short8 bfr = *reinterpret_cast<const short8*>(&wb[(ocW + ni * 16 + l15) * 8]);
#pragma unroll
                    for (int mi = 0; mi < 4; ++mi)
                        acc[mi][ni] = __builtin_amdgcn_mfma_f32_16x16x32_bf16(a[mi], bfr, acc[mi][ni], 0, 0, 0);
                }
            }
        }

#pragma unroll
        for (int ni = 0; ni < 4; ++ni) {
            float s = 0.f, qq = 0.f;
#pragma unroll
            for (int mi = 0; mi < 4; ++mi)
#pragma unroll
                for (int e = 0; e < 4; ++e) {
                    float v = acc[mi][ni][e];
                    s += v; qq = fmaf(v, v, qq);
                }
            s += __shfl_xor(s, 16); s += __shfl_xor(s, 32);
            qq += __shfl_xor(qq, 16); qq += __shfl_xor(qq, 32);
            if (lane < 16) {
                atomicAdd(&sums[512 + ocW + ni * 16 + l15], s);
                atomicAdd(&sums[768 + ocW + ni * 16 + l15], qq);
            }
        }

        __syncthreads();
        float* T = Ts + w * 1088;
#pragma unroll
        for (int mi = 0; mi < 4; ++mi) {
#pragma unroll
            for (int ni = 0; ni < 4; ++ni)
#pragma unroll
                for (int e = 0; e < 4; ++e)
                    T[(ni * 16 + l15) * 17 + q * 4 + e] = acc[mi][ni][e];
#pragma unroll
            for (int eo = 0; eo < 16; ++eo) {
                int ocl = eo * 4 + q;
                float v = T[ocl * 17 + l15];
                y_reg[(size_t)n * 262144 + (size_t)(ocW + ocl) * 1024 + pt * 128 + wm * 64 + mi * 16 + l15] = f2bf(v);
            }
        }
    } else {
        // ================= conv_cls =================
        const int sub = blockIdx.x - 1024;
        const int n0 = (sub & 31) * 2;
        const int ob = sub >> 5;
        const int ocW = ob * 128 + wn * 64;

        for (int f = tid; f < 200; f += 256) {
            int n_l = f / 100, rem = f % 100;
            int rr = rem / 10, cc = rem % 10;
            float v = 0.f;
            if (rr >= 1 && rr <= 8 && cc >= 1 && cc <= 8)
                v = dsig(fdec(ds_enc[(n0 + n_l) * 64 + (rr - 1) * 8 + (cc - 1)]));
            Ds[f] = f2bf(v);
        }
        __syncthreads();
        {
            short8 ad[4];
#pragma unroll
            for (int mi = 0; mi < 4; ++mi) {
                int pos = mi * 16 + l15;
                int r = pos >> 3, c = pos & 7;
                short8 v = {0, 0, 0, 0, 0, 0, 0, 0};
#pragma unroll
                for (int j = 0; j < 8; ++j) {
                    int k = q * 8 + j;
                    if (k < 9) {
                        int ky = k / 3, kx = k % 3;
                        v[j] = (short)Ds[wm * 100 + (r + ky) * 10 + (c + kx)];
                    }
                }
                ad[mi] = v;
            }
#pragma unroll
            for (int ni = 0; ni < 4; ++ni) {
                short8 bfr = *reinterpret_cast<const short8*>(&wtdc[(q * 256 + ocW + ni * 16 + l15) * 8]);
#pragma unroll
                for (int mi = 0; mi < 4; ++mi)
                    acc[mi][ni] = __builtin_amdgcn_mfma_f32_16x16x32_bf16(ad[mi], bfr, acc[mi][ni], 0, 0, 0);
            }
        }

        int ldso[4]; size_t go[4]; bool gv[4], wvld[4];
#pragma unroll
        for (int it = 0; it < 4; ++it) {
            int f = tid + 256 * it;
            int cell = f >> 2, chn = f & 3;
            int n_l = cell / 100, rem = cell % 100;
            int rr = rem / 10, cc = rem % 10;
            wvld[it] = (f < 800);
            gv[it] = wvld[it] && rr >= 1 && rr <= 8 && cc >= 1 && cc <= 8;
            go[it] = ((size_t)((n0 + n_l) * 64 + (rr - 1) * 8 + (cc - 1))) * 256 + chn * 8;
            ldso[it] = cell * 40 + chn * 8;
        }
        short8 st[4];
#pragma unroll
        for (int it = 0; it < 4; ++it) {
            short8 v = {0, 0, 0, 0, 0, 0, 0, 0};
            if (gv[it]) v = *reinterpret_cast<const short8*>(&zt[go[it]]);
            st[it] = v;
        }
        for (int kc = 0; kc < 8; ++kc) {
            unsigned short* As = (kc & 1) ? As1 : As0;
#pragma unroll
            for (int it = 0; it < 4; ++it)
                if (wvld[it]) *reinterpret_cast<short8*>(&As[ldso[it]]) = st[it];
            if (kc < 7) {
#pragma unroll
                for (int it = 0; it < 4; ++it) {
                    short8 v = {0, 0, 0, 0, 0, 0, 0, 0};
                    if (gv[it]) v = *reinterpret_cast<const short8*>(&zt[go[it] + (kc + 1) * 32]);
                    st[it] = v;
                }
            }
            barrier_lgkm();
#pragma unroll
            for (int tap = 0; tap < 9; ++tap) {
                const int ky = tap / 3, kx = tap % 3;
                short8 a[4];
#pragma unroll
                for (int mi = 0; mi < 4; ++mi) {
                    int pos = mi * 16 + l15;
                    int r = (pos >> 3) + ky, c = (pos & 7) + kx;
                    a[mi] = *reinterpret_cast<const short8*>(&As[(wm * 100 + r * 10 + c) * 40 + q * 8]);
                }
                const unsigned short* wb = wtc + (size_t)(((tap * 8 + kc) * 4 + q) * 256) * 8;
#pragma unroll
                for (int ni = 0; ni < 4; ++ni) {
                    short8 bfr = *reinterpret_cast<const short8*>(&wb[(ocW + ni * 16 + l15) * 8]);
#pragma unroll
                    for (int mi = 0; mi < 4; ++mi)
                        acc[mi][ni] = __builtin_amdgcn_mfma_f32_16x16x32_bf16(a[mi], bfr, acc[mi][ni], 0, 0, 0);
                }
            }
        }

#pragma unroll
        for (int ni = 0; ni < 4; ++ni) {
            float s = 0.f, qq = 0.f;
#pragma unroll
            for (int mi = 0; mi < 4; ++mi)
#pragma unroll
                for (int e = 0; e < 4; ++e) {
                    float v = acc[mi][ni][e];
                    s += v; qq = fmaf(v, v, qq);
                }
            s += __shfl_xor(s, 16); s += __shfl_xor(s, 32);
            qq += __shfl_xor(qq, 16); qq += __shfl_xor(qq, 32);
            if (lane < 16) {
                atomicAdd(&sums[0 + ocW + ni * 16 + l15], s);
                atomicAdd(&sums[256 + ocW + ni * 16 + l15], qq);
            }
        }

        __syncthreads();
        float* T = Ts + w * 1088;
#pragma unroll
        for (int mi = 0; mi < 4; ++mi) {
#pragma unroll
            for (int ni = 0; ni < 4; ++ni)
#pragma unroll
                for (int e = 0; e < 4; ++e)
                    T[(ni * 16 + l15) * 17 + q * 4 + e] = acc[mi][ni][e];
#pragma unroll
            for (int eo = 0; eo < 16; ++eo) {
                int ocl = eo * 4 + q;
                float v = T[ocl * 17 + l15];
                y_cls[(size_t)(n0 + wm) * 16384 + (size_t)(ocW + ocl) * 64 + mi * 16 + l15] = f2bf(v);
            }
        }
    }
}

// ---------------------------------------------------------------- lin (lin_reg2 + lin_cls merged, BN folded)
__global__ __launch_bounds__(256) void k_lin(
    const unsigned short* __restrict__ y_reg, const unsigned short* __restrict__ y_cls,
    const float* __restrict__ sums,
    const float* __restrict__ g_cls, const float* __restrict__ b_cls,
    const float* __restrict__ g_reg, const float* __restrict__ b_reg,
    const float* __restrict__ w_reg, const float* __restrict__ w_cls,
    float* __restrict__ part, float* __restrict__ out_cls) {
    __shared__ __align__(16) char smem[35328];
    const int tid = threadIdx.x;
    const int wv = tid >> 6, lane = tid & 63;
    const int l15 = lane & 15, q = lane >> 4;

    if (blockIdx.x < 512) {
        // ================= lin_reg2 =================
        unsigned short* A_l = (unsigned short*)smem;         // 32*520 ushorts = 33280 B
        float* ss_l = (float*)(smem + 33280);                // 512 f32
        {
            float mean = sums[512 + tid] * (1.f / 65536.f);
            float var = sums[768 + tid] * (1.f / 65536.f) - mean * mean;
            float sc = g_reg[tid] * rsqrtf(var + 1e-5f);
            ss_l[tid] = sc;
            ss_l[256 + tid] = b_reg[tid] - mean * sc;
        }
        const int k0 = blockIdx.x * 512;
        const int jw = wv * 80;

        f32x4 acc[5][4];
#pragma unroll
        for (int ni = 0; ni < 5; ++ni)
#pragma unroll
            for (int mi = 0; mi < 4; ++mi) acc[ni][mi] = (f32x4){0.f, 0.f, 0.f, 0.f};

        for (int scn = 0; scn < 2; ++scn) {
            const int ksub = k0 + scn * 256;
            const int ch = ksub >> 10;
            __syncthreads();
            const float scf = ss_l[ch], shf = ss_l[256 + ch];
            {
                const int c = tid & 31, nb = tid >> 5;
#pragma unroll
                for (int p = 0; p < 8; ++p) {
                    const int n = p * 8 + nb;
                    short8 v = *reinterpret_cast<const short8*>(&y_reg[(size_t)n * 262144 + ksub + c * 8]);
                    float f[8];
#pragma unroll
                    for (int j = 0; j < 8; ++j)
                        f[j] = fmaxf(fmaf(bf2f((unsigned short)v[j]), scf, shf), 0.f);
                    *reinterpret_cast<short8*>(&A_l[c * 520 + n * 8]) = pack8_trunc(f);
                }
            }
            __syncthreads();
            // 2-deep W pipeline: load kk+1 while packing/MFMA-ing kk
            float4 w0[5], w1[5];
#pragma unroll
            for (int ni = 0; ni < 5; ++ni) {
                const float* wp = &w_reg[(size_t)(jw + ni * 16 + l15) * 262144 + ksub + q * 8];
                w0[ni] = *reinterpret_cast<const float4*>(wp);
                w1[ni] = *reinterpret_cast<const float4*>(wp + 4);
            }
#pragma unroll
            for (int kk = 0; kk < 8; ++kk) {
                short8 b[5];
#pragma unroll
                for (int ni = 0; ni < 5; ++ni) {
                    float f[8] = {w0[ni].x, w0[ni].y, w0[ni].z, w0[ni].w,
                                  w1[ni].x, w1[ni].y, w1[ni].z, w1[ni].w};
                    b[ni] = pack8_trunc(f);
                }
                if (kk < 7) {
#pragma unroll
                    for (int ni = 0; ni < 5; ++ni) {
                        const float* wp = &w_reg[(size_t)(jw + ni * 16 + l15) * 262144 + ksub + (kk + 1) * 32 + q * 8];
                        w0[ni] = *reinterpret_cast<const float4*>(wp);
                        w1[ni] = *reinterpret_cast<const float4*>(wp + 4);
                    }
                }
                short8 a[4];
#pragma unroll
                for (int mi = 0; mi < 4; ++mi)
                    a[mi] = *reinterpret_cast<const short8*>(&A_l[(kk * 4 + q) * 520 + (mi * 16 + l15) * 8]);
#pragma unroll
                for (int ni = 0; ni < 5; ++ni)
#pragma unroll
                    for (int mi = 0; mi < 4; ++mi)
                        acc[ni][mi] = __builtin_amdgcn_mfma_f32_16x16x32_bf16(a[mi], b[ni], acc[ni][mi], 0, 0, 0);
            }
        }

        float* pb = part + (size_t)blockIdx.x * 20480;
#pragma unroll
        for (int ni = 0; ni < 5; ++ni) {
            const int j = jw + ni * 16 + l15;
#pragma unroll
            for (int mi = 0; mi < 4; ++mi)
#pragma unroll
                for (int e = 0; e < 4; ++e) {
                    const int n = mi * 16 + q * 4 + e;
                    pb[n * 320 + j] = acc[ni][mi][e];
                }
        }
    } else {
        // ================= lin_cls =================
        float* ss_l = (float*)smem;                          // 512 f32
        {
            float mean = sums[tid] * (1.f / 4096.f);
            float var = sums[256 + tid] * (1.f / 4096.f) - mean * mean;
            float sc = g_cls[tid] * rsqrtf(var + 1e-5f);
            ss_l[tid] = sc;
            ss_l[256 + tid] = b_cls[tid] - mean * sc;
        }
        __syncthreads();
        const int kb = (blockIdx.x - 512) * 256;
        const int q4 = q;
        f32x4 acc[5];
#pragma unroll
        for (int ni = 0; ni < 5; ++ni) acc[ni] = (f32x4){0.f, 0.f, 0.f, 0.f};
#pragma unroll
        for (int ks = 0; ks < 8; ++ks) {
            const int kx = kb + ks * 32 + q4 * 8;
            short8 yv = *reinterpret_cast<const short8*>(&y_cls[(wv * 16 + l15) * 16384 + kx]);
            const int ch = kx >> 6;
            const float sc = ss_l[ch], sh = ss_l[256 + ch];
            float f[8];
#pragma unroll
            for (int j = 0; j < 8; ++j) f[j] = fmaxf(fmaf(bf2f((unsigned short)yv[j]), sc, sh), 0.f);
            short8 a = pack8_trunc(f);
#pragma unroll
            for (int ni = 0; ni < 5; ++ni) {
                const float* wp = &w_cls[(size_t)(ni * 16 + l15) * 16384 + kx];
                float4 b0 = *reinterpret_cast<const float4*>(wp);
                float4 b1 = *reinterpret_cast<const float4*>(wp + 4);
                float g[8] = {b0.x, b0.y, b0.z, b0.w, b1.x, b1.y, b1.z, b1.w};
                acc[ni] = __builtin_amdgcn_mfma_f32_16x16x32_bf16(a, pack8_trunc(g), acc[ni], 0, 0, 0);
            }
        }
#pragma unroll
        for (int ni = 0; ni < 5; ++ni)
#pragma unroll
            for (int e = 0; e < 4; ++e)
                atomicAdd(&out_cls[(wv * 16 + q4 * 4 + e) * 80 + ni * 16 + l15], acc[ni][e]);
    }
}

// reduce: out[n][j] (+= bias, pre-seeded) over 512 partial blocks; grid (80, 8)
__global__ __launch_bounds__(256) void k_lin_red(const float* __restrict__ part, float* __restrict__ out_loc) {
    const int idx = blockIdx.x * 256 + threadIdx.x;       // 0..20479
    const int b0 = blockIdx.y * 64;
    float s0 = 0.f, s1 = 0.f, s2 = 0.f, s3 = 0.f;
#pragma unroll 4
    for (int b = 0; b < 64; b += 4) {
        s0 += part[(size_t)(b0 + b + 0) * 20480 + idx];
        s1 += part[(size_t)(b0 + b + 1) * 20480 + idx];
        s2 += part[(size_t)(b0 + b + 2) * 20480 + idx];
        s3 += part[(size_t)(b0 + b + 3) * 20480 + idx];
    }
    atomicAdd(&out_loc[idx], (s0 + s1) + (s2 + s3));
}

// ---------------------------------------------------------------- launch
extern "C" void kernel_launch(void* const* d_in, const int* in_sizes, int n_in,
                              void* d_out, int out_size, void* d_ws, size_t ws_size,
                              hipStream_t stream) {
    const float* z_f        = (const float*)d_in[0];
    const float* x_f        = (const float*)d_in[1];
    const float* conv_cls_w = (const float*)d_in[2];
    const float* bn_cls_g   = (const float*)d_in[3];
    const float* bn_cls_b   = (const float*)d_in[4];
    const float* conv_reg_w = (const float*)d_in[5];
    const float* bn_reg_g   = (const float*)d_in[6];
    const float* bn_reg_b   = (const float*)d_in[7];
    const float* lin_cls_w  = (const float*)d_in[8];
    const float* lin_cls_b  = (const float*)d_in[9];
    const float* lin_reg_w  = (const float*)d_in[10];
    const float* lin_reg_b  = (const float*)d_in[11];

    float* out = (float*)d_out;
    float* ws  = (float*)d_ws;
    unsigned* ds_enc = (unsigned*)(ws + WS_DS_ENC);
    float* dist_t = ws + WS_DT;
    float* sums   = ws + WS_SUMS;
    unsigned short* y_cls = (unsigned short*)(ws + WS_YCLS);
    unsigned short* y_reg = (unsigned short*)(ws + WS_YREG);
    unsigned short* xt    = (unsigned short*)(ws + WS_XT);
    unsigned short* zt    = (unsigned short*)(ws + WS_ZT);
    unsigned short* wtr   = (unsigned short*)(ws + WS_WTR);
    unsigned short* wtdr  = (unsigned short*)(ws + WS_WTDR);
    unsigned short* wtc   = (unsigned short*)(ws + WS_WTC);
    unsigned short* wtdc  = (unsigned short*)(ws + WS_WTDC);
    float* part   = ws + WS_PART;
    float* xsq    = ws + WS_XSQ;
    float* zsq    = ws + WS_ZSQ;

    hipLaunchKernelGGL(k_prep, dim3(2776), dim3(256), 0, stream,
                       x_f, z_f, conv_reg_w, conv_cls_w, xt, zt, xsq, zsq,
                       wtr, wtdr, wtc, wtdc, ds_enc, sums, out, out + 5120, lin_cls_b, lin_reg_b);
    hipLaunchKernelGGL(k_dist, dim3(4, 64), dim3(256), 0, stream, zt, xt, zsq, xsq, dist_t, ds_enc);
    hipLaunchKernelGGL(k_conv, dim3(1088), dim3(256), 0, stream,
                       xt, dist_t, zt, ds_enc, wtr, wtdr, wtc, wtdc, y_reg, y_cls, sums);
    hipLaunchKernelGGL(k_lin, dim3(576), dim3(256), 0, stream,
                       y_reg, y_cls, sums, bn_cls_g, bn_cls_b, bn_reg_g, bn_reg_b,
                       lin_reg_w, lin_cls_w, part, out);
    hipLaunchKernelGGL(k_lin_red, dim3(80, 8), dim3(256), 0, stream, part, out + 5120);
}

// Round 3
// 755.709 us; speedup vs baseline: 1.2136x; 1.0076x over previous
//
#include <hip/hip_runtime.h>
#include <math.h>

typedef short short8 __attribute__((ext_vector_type(8)));
typedef float f32x4 __attribute__((ext_vector_type(4)));
typedef unsigned int uint4v __attribute__((ext_vector_type(4)));

// ---------------- workspace layout (float offsets) ----------------
#define WS_DS_ENC 0            // 4096 u32
#define WS_DT     4096         // 65536 f32
#define WS_SUMS   69632        // 1024 f32
#define WS_YCLS   71680        // 1,048,576 ushort  [n][256][64] bf16
#define WS_YREG   595968       // 16,777,216 ushort [n][256][1024] bf16
#define WS_XT     8984576      // 16,777,216 ushort [n][32][32][256] bf16
#define WS_ZT     17373184     // 1,048,576 ushort  [n][64][256] bf16
#define WS_WTR    17897472     // 589,824 ushort  [9][8][4][256][8]
#define WS_WTDR   18192384     // 8,192 ushort    [4][256][8]
#define WS_WTC    18196480     // 589,824 ushort
#define WS_WTDC   18491392     // 8,192 ushort
#define WS_PART   18495488     // 10,485,760 f32  [512][64][320] lin_reg partials
#define WS_XSQ    28981248     // 65,536 f32  [n][1024]
#define WS_ZSQ    29046784     // 4,096 f32   [n][64]

__device__ __forceinline__ float dsig(float d) {
    return 4.0f / (1.0f + __expf(d)) - 1.0f;
}
__device__ __forceinline__ unsigned fenc(float f) {
    unsigned u = __float_as_uint(f);
    return (u & 0x80000000u) ? ~u : (u | 0x80000000u);
}
__device__ __forceinline__ float fdec(unsigned e) {
    unsigned u = (e & 0x80000000u) ? (e ^ 0x80000000u) : ~e;
    return __uint_as_float(u);
}
__device__ __forceinline__ unsigned short f2bf(float f) {   // RNE
    unsigned u = __float_as_uint(f);
    return (unsigned short)((u + 0x7fffu + ((u >> 16) & 1u)) >> 16);
}
__device__ __forceinline__ float bf2f(unsigned short h) {
    return __uint_as_float(((unsigned)h) << 16);
}
__device__ __forceinline__ short8 pack8_trunc(const float* f) {
    uint4v u;
#pragma unroll
    for (int i = 0; i < 4; ++i) {
        unsigned lo = __float_as_uint(f[2 * i]) >> 16;
        unsigned hi = __float_as_uint(f[2 * i + 1]) & 0xffff0000u;
        u[i] = lo | hi;
    }
    return __builtin_bit_cast(short8, u);
}
// raw barrier: LDS writes visible, prefetch global loads stay in flight (no vmcnt drain)
__device__ __forceinline__ void barrier_lgkm() {
    asm volatile("s_waitcnt lgkmcnt(0)" ::: "memory");
    __builtin_amdgcn_s_barrier();
    __builtin_amdgcn_sched_barrier(0);
}

// ---------------------------------------------------------------- prep: xt + zt + wswz + init (merged)
__global__ __launch_bounds__(256) void k_prep(
    const float* __restrict__ x, const float* __restrict__ z,
    const float* __restrict__ wr, const float* __restrict__ wc,
    unsigned short* __restrict__ xt, unsigned short* __restrict__ zt,
    float* __restrict__ xsq, float* __restrict__ zsq,
    unsigned short* __restrict__ wtr, unsigned short* __restrict__ wtdr,
    unsigned short* __restrict__ wtc, unsigned short* __restrict__ wtdc,
    unsigned* __restrict__ ds_enc, float* __restrict__ sums,
    float* __restrict__ out_cls, float* __restrict__ out_loc,
    const float* __restrict__ lin_cls_b, const float* __restrict__ lin_reg_b) {
    __shared__ __align__(16) char pmem[17920];
    const int b = blockIdx.x;
    const int tid = threadIdx.x;
    if (b < 2048) {                       // ---- xt transpose + xsq
        float* t = (float*)pmem;
        float* xr = (float*)(pmem + 8448);
        const int n = b >> 5, row = b & 31;
        const int col = tid & 31, g = tid >> 5;
        float sq = 0.f;
        for (int c4 = 0; c4 < 4; ++c4) {
            const int ic0 = c4 * 64;
            __syncthreads();
            {
                int icl = tid >> 2, cg = tid & 3;
                const float* src = &x[((n * 256 + ic0 + icl) * 32 + row) * 32 + cg * 8];
                float4 a = *reinterpret_cast<const float4*>(src);
                float4 bb = *reinterpret_cast<const float4*>(src + 4);
                float* d = &t[icl * 33 + cg * 8];
                d[0] = a.x; d[1] = a.y; d[2] = a.z; d[3] = a.w;
                d[4] = bb.x; d[5] = bb.y; d[6] = bb.z; d[7] = bb.w;
            }
            __syncthreads();
            {
                short8 v;
#pragma unroll
                for (int j = 0; j < 8; ++j) {
                    float f = t[(g * 8 + j) * 33 + col];
                    sq = fmaf(f, f, sq);
                    v[j] = (short)f2bf(f);
                }
                *reinterpret_cast<short8*>(&xt[((n * 32 + row) * 32 + col) * 256 + ic0 + g * 8]) = v;
            }
        }
        sq += __shfl_xor(sq, 32);
        if ((tid & 63) < 32) xr[(tid >> 6) * 32 + col] = sq;
        __syncthreads();
        if (tid < 32) xsq[(n * 32 + row) * 32 + tid] = xr[tid] + xr[32 + tid] + xr[64 + tid] + xr[96 + tid];
    } else if (b < 2112) {                // ---- zt transpose + zsq
        float* t = (float*)pmem;
        float* zr = (float*)(pmem + 16640);
        const int n = b - 2048;
        const int pos = tid & 63, gg = tid >> 6;
        float sq = 0.f;
        for (int c4 = 0; c4 < 4; ++c4) {
            const int ic0 = c4 * 64;
            __syncthreads();
            {
                int icl = tid >> 2, pg = tid & 3;
                const float* src = &z[(n * 256 + ic0 + icl) * 64 + pg * 16];
#pragma unroll
                for (int r = 0; r < 4; ++r) {
                    float4 a = *reinterpret_cast<const float4*>(src + r * 4);
                    float* d = &t[icl * 65 + pg * 16 + r * 4];
                    d[0] = a.x; d[1] = a.y; d[2] = a.z; d[3] = a.w;
                }
            }
            __syncthreads();
            {
                short8 v0, v1;
#pragma unroll
                for (int j = 0; j < 8; ++j) {
                    float f = t[(gg * 16 + j) * 65 + pos];
                    sq = fmaf(f, f, sq);
                    v0[j] = (short)f2bf(f);
                }
#pragma unroll
                for (int j = 0; j < 8; ++j) {
                    float f = t[(gg * 16 + 8 + j) * 65 + pos];
                    sq = fmaf(f, f, sq);
                    v1[j] = (short)f2bf(f);
                }
                unsigned short* d = &zt[(n * 64 + pos) * 256 + ic0 + gg * 16];
                *reinterpret_cast<short8*>(d) = v0;
                *reinterpret_cast<short8*>(d + 8) = v1;
            }
        }
        zr[gg * 64 + pos] = sq;
        __syncthreads();
        if (tid < 64) zsq[n * 64 + tid] = zr[tid] + zr[64 + tid] + zr[128 + tid] + zr[192 + tid];
    } else if (b < 2696) {                // ---- weight swizzle
        const int sub = b - 2112;
        const int by = sub / 292, bx = sub % 292;
        const int idx = bx * 256 + tid;
        const float* src = by ? wc : wr;
        unsigned short* dw = by ? wtc : wtr;
        unsigned short* dd = by ? wtdc : wtdr;
        if (idx < 73728) {
            int tap = idx >> 13, rem = idx & 8191;
            int kc = rem >> 10, rem2 = rem & 1023;
            int q = rem2 >> 8, oc = rem2 & 255;
            short8 v;
#pragma unroll
            for (int j = 0; j < 8; ++j) {
                int icg = 1 + kc * 32 + q * 8 + j;
                v[j] = (short)f2bf(src[(oc * 257 + icg) * 9 + tap]);
            }
            *reinterpret_cast<short8*>(&dw[idx * 8]) = v;
        } else if (idx < 74752) {
            int i2 = idx - 73728;
            int q = i2 >> 8, oc = i2 & 255;
            short8 v;
#pragma unroll
            for (int j = 0; j < 8; ++j) {
                int k = q * 8 + j;
                v[j] = (k < 9) ? (short)f2bf(src[(oc * 257) * 9 + k]) : (short)0;
            }
            *reinterpret_cast<short8*>(&dd[i2 * 8]) = v;
        }
    } else {                              // ---- init
        const int i = (b - 2696) * 256 + tid;
        if (i < 4096) ds_enc[i] = 0u;
        if (i < 1024) sums[i] = 0.0f;
        if (i < 5120) out_cls[i] = lin_cls_b[i % 80];
        if (i < 20480) out_loc[i] = lin_reg_b[i % 320];
    }
}

// ---------------------------------------------------------------- dist (MFMA)
__global__ __launch_bounds__(256) void k_dist(const unsigned short* __restrict__ zt,
                                              const unsigned short* __restrict__ xt,
                                              const float* __restrict__ zsq, const float* __restrict__ xsq,
                                              float* __restrict__ dist_t, unsigned* __restrict__ ds_enc) {
    const int n = blockIdx.y;
    const int tid = threadIdx.x;
    const int wv = tid >> 6, lane = tid & 63;
    const int l15 = lane & 15, q4 = lane >> 4;
    const int q0 = blockIdx.x * 256 + wv * 64;
    const unsigned short* zb = zt + n * 16384;
    const unsigned short* xb = xt + (size_t)(n * 1024 + q0) * 256;

    f32x4 acc[4][4];
#pragma unroll
    for (int mi = 0; mi < 4; ++mi)
#pragma unroll
        for (int ni = 0; ni < 4; ++ni) acc[mi][ni] = (f32x4){0.f, 0.f, 0.f, 0.f};

#pragma unroll
    for (int ks = 0; ks < 8; ++ks) {
        short8 a[4], b[4];
#pragma unroll
        for (int mi = 0; mi < 4; ++mi)
            a[mi] = *reinterpret_cast<const short8*>(&zb[(mi * 16 + l15) * 256 + ks * 32 + q4 * 8]);
#pragma unroll
        for (int ni = 0; ni < 4; ++ni)
            b[ni] = *reinterpret_cast<const short8*>(&xb[(ni * 16 + l15) * 256 + ks * 32 + q4 * 8]);
#pragma unroll
        for (int ni = 0; ni < 4; ++ni)
#pragma unroll
            for (int mi = 0; mi < 4; ++mi)
                acc[mi][ni] = __builtin_amdgcn_mfma_f32_16x16x32_bf16(a[mi], b[ni], acc[mi][ni], 0, 0, 0);
    }

    float zs[4][4];
#pragma unroll
    for (int mi = 0; mi < 4; ++mi)
#pragma unroll
        for (int e = 0; e < 4; ++e) zs[mi][e] = zsq[n * 64 + mi * 16 + q4 * 4 + e];
    float xq[4];
#pragma unroll
    for (int ni = 0; ni < 4; ++ni) xq[ni] = xsq[n * 1024 + q0 + ni * 16 + l15];

#pragma unroll
    for (int ni = 0; ni < 4; ++ni) {
        float m = -1e30f;
#pragma unroll
        for (int mi = 0; mi < 4; ++mi)
#pragma unroll
            for (int e = 0; e < 4; ++e)
                m = fmaxf(m, zs[mi][e] - 2.f * acc[mi][ni][e]);
        m = fmaxf(m, __shfl_xor(m, 16));
        m = fmaxf(m, __shfl_xor(m, 32));
        if (lane < 16) dist_t[n * 1024 + q0 + ni * 16 + l15] = dsig(m + xq[ni]);
    }
#pragma unroll
    for (int mi = 0; mi < 4; ++mi)
#pragma unroll
        for (int e = 0; e < 4; ++e) {
            float v = -1e30f;
#pragma unroll
            for (int ni = 0; ni < 4; ++ni) v = fmaxf(v, xq[ni] - 2.f * acc[mi][ni][e]);
            v = fmaxf(v, __shfl_xor(v, 1));
            v = fmaxf(v, __shfl_xor(v, 2));
            v = fmaxf(v, __shfl_xor(v, 4));
            v = fmaxf(v, __shfl_xor(v, 8));
            if (l15 == 0) atomicMax(&ds_enc[n * 64 + mi * 16 + q4 * 4 + e], fenc(zs[mi][e] + v));
        }
}

// ---------------------------------------------------------------- conv (8-wave blocks; reg M=256, cls on waves 0-3)
__global__ __launch_bounds__(512) void k_conv(
    const unsigned short* __restrict__ xt, const float* __restrict__ dist_t,
    const unsigned short* __restrict__ zt, const unsigned* __restrict__ ds_enc,
    const unsigned short* __restrict__ wtr, const unsigned short* __restrict__ wtdr,
    const unsigned short* __restrict__ wtc, const unsigned short* __restrict__ wtdc,
    unsigned short* __restrict__ y_reg, unsigned short* __restrict__ y_cls,
    float* __restrict__ sums) {
    __shared__ __align__(16) char smem[55104];
    unsigned short* As0 = (unsigned short*)smem;             // 27200 B
    unsigned short* As1 = (unsigned short*)(smem + 27200);   // 27200 B
    unsigned short* Ds = (unsigned short*)(smem + 54400);    // 680 B
    float* Ts = (float*)smem;

    const int tid = threadIdx.x;
    const int w = tid >> 6, lane = tid & 63;
    const int l15 = lane & 15, q = lane >> 4;

    f32x4 acc[4][4];
#pragma unroll
    for (int mi = 0; mi < 4; ++mi)
#pragma unroll
        for (int ni = 0; ni < 4; ++ni) acc[mi][ni] = (f32x4){0.f, 0.f, 0.f, 0.f};

    if (blockIdx.x < 512) {
        // ================= conv_reg: 8 rows (M=256 pix), 8 waves wm=w&3, wn=w>>2 =================
        const int n = blockIdx.x >> 3, sb = blockIdx.x & 7;
        const int pt8 = sb >> 1, ot = sb & 1;
        const int wm = w & 3, wn = w >> 2;
        const int ocW = ot * 128 + wn * 64;

        for (int f = tid; f < 340; f += 512) {
            int rr = f / 34, cc = f % 34;
            int prow = pt8 * 8 + rr;
            float v = 0.f;
            if (prow >= 1 && prow <= 32 && cc >= 1 && cc <= 32)
                v = dist_t[n * 1024 + (prow - 1) * 32 + (cc - 1)];
            Ds[f] = f2bf(v);
        }
        __syncthreads();
        {
            short8 ad[4];
#pragma unroll
            for (int mi = 0; mi < 4; ++mi) {
                int m = wm * 64 + mi * 16 + l15;
                int r = m >> 5, c = m & 31;
                short8 v = {0, 0, 0, 0, 0, 0, 0, 0};
#pragma unroll
                for (int j = 0; j < 8; ++j) {
                    int k = q * 8 + j;
                    if (k < 9) {
                        int ky = k / 3, kx = k % 3;
                        v[j] = (short)Ds[(r + ky) * 34 + (c + kx)];
                    }
                }
                ad[mi] = v;
            }
#pragma unroll
            for (int ni = 0; ni < 4; ++ni) {
                short8 bfr = *reinterpret_cast<const short8*>(&wtdr[(q * 256 + ocW + ni * 16 + l15) * 8]);
#pragma unroll
                for (int mi = 0; mi < 4; ++mi)
                    acc[mi][ni] = __builtin_amdgcn_mfma_f32_16x16x32_bf16(ad[mi], bfr, acc[mi][ni], 0, 0, 0);
            }
        }

        // staging geometry: 1360 short8 items, 3 slots per thread
        int ldso[3]; size_t go[3]; bool gv[3], wvld[3];
#pragma unroll
        for (int it = 0; it < 3; ++it) {
            int f = tid + 512 * it;
            int cell = f >> 2, chn = f & 3;
            int rr = cell / 34, cc = cell % 34;
            int prow = pt8 * 8 + rr;
            wvld[it] = (f < 1360);
            gv[it] = wvld[it] && prow >= 1 && prow <= 32 && cc >= 1 && cc <= 32;
            go[it] = ((size_t)(n * 32 + prow - 1) * 32 + (cc - 1)) * 256 + chn * 8;
            ldso[it] = cell * 40 + chn * 8;
        }
        short8 st[3];
#pragma unroll
        for (int it = 0; it < 3; ++it) {
            short8 v = {0, 0, 0, 0, 0, 0, 0, 0};
            if (gv[it]) v = *reinterpret_cast<const short8*>(&xt[go[it]]);
            st[it] = v;
        }
        for (int kc = 0; kc < 8; ++kc) {
            unsigned short* As = (kc & 1) ? As1 : As0;
#pragma unroll
            for (int it = 0; it < 3; ++it)
                if (wvld[it]) *reinterpret_cast<short8*>(&As[ldso[it]]) = st[it];
            if (kc < 7) {
#pragma unroll
                for (int it = 0; it < 3; ++it) {
                    short8 v = {0, 0, 0, 0, 0, 0, 0, 0};
                    if (gv[it]) v = *reinterpret_cast<const short8*>(&xt[go[it] + (kc + 1) * 32]);
                    st[it] = v;
                }
            }
            barrier_lgkm();
#pragma unroll
            for (int tap = 0; tap < 9; ++tap) {
                const int ky = tap / 3, kx = tap % 3;
                short8 a[4];
#pragma unroll
                for (int mi = 0; mi < 4; ++mi) {
                    int m = wm * 64 + mi * 16 + l15;
                    int r = (m >> 5) + ky, c = (m & 31) + kx;
                    a[mi] = *reinterpret_cast<const short8*>(&As[(r * 34 + c) * 40 + q * 8]);
                }
                const unsigned short* wb = wtr + (size_t)(((tap * 8 + kc) * 4 + q) * 256) * 8;
#pragma unroll
                for (int ni = 0; ni < 4; ++ni) {
                    short8 bfr = *reinterpret_cast<const short8*>(&wb[(ocW + ni * 16 + l15) * 8]);
#pragma unroll
                    for (int mi = 0; mi < 4; ++mi)
                        acc[mi][ni] = __builtin_amdgcn_mfma_f32_16x16x32_bf16(a[mi], bfr, acc[mi][ni], 0, 0, 0);
                }
            }
        }

#pragma unroll
        for (int ni = 0; ni < 4; ++ni) {
            float s = 0.f, qq = 0.f;
#pragma unroll
            for (int mi = 0; mi < 4; ++mi)
#pragma unroll
                for (int e = 0; e < 4; ++e) {
                    float v = acc[mi][ni][e];
                    s += v; qq = fmaf(v, v, qq);
                }
            s += __shfl_xor(s, 16); s += __shfl_xor(s, 32);
            qq += __shfl_xor(qq, 16); qq += __shfl_xor(qq, 32);
            if (lane < 16) {
                atomicAdd(&sums[512 + ocW + ni * 16 + l15], s);
                atomicAdd(&sums[768 + ocW + ni * 16 + l15], qq);
            }
        }

        __syncthreads();
        float* T = Ts + w * 1088;
#pragma unroll
        for (int mi = 0; mi < 4; ++mi) {
#pragma unroll
            for (int ni = 0; ni < 4; ++ni)
#pragma unroll
                for (int e = 0; e < 4; ++e)
                    T[(ni * 16 + l15) * 17 + q * 4 + e] = acc[mi][ni][e];
#pragma unroll
            for (int eo = 0; eo < 16; ++eo) {
                int ocl = eo * 4 + q;
                float v = T[ocl * 17 + l15];
                y_reg[(size_t)n * 262144 + (size_t)(ocW + ocl) * 1024 + pt8 * 256 + wm * 64 + mi * 16 + l15] = f2bf(v);
            }
        }
    } else {
        // ================= conv_cls: compute on waves 0-3, all waves stage & hit barriers =================
        const int sub = blockIdx.x - 512;
        const int n0 = (sub & 31) * 2;
        const int ob = sub >> 5;
        const int wm = w & 1, wn = (w >> 1) & 1;
        const int ocW = ob * 128 + wn * 64;
        const bool act = (w < 4);

        for (int f = tid; f < 200; f += 512) {
            int n_l = f / 100, rem = f % 100;
            int rr = rem / 10, cc = rem % 10;
            float v = 0.f;
            if (rr >= 1 && rr <= 8 && cc >= 1 && cc <= 8)
                v = dsig(fdec(ds_enc[(n0 + n_l) * 64 + (rr - 1) * 8 + (cc - 1)]));
            Ds[f] = f2bf(v);
        }
        __syncthreads();
        if (act) {
            short8 ad[4];
#pragma unroll
            for (int mi = 0; mi < 4; ++mi) {
                int pos = mi * 16 + l15;
                int r = pos >> 3, c = pos & 7;
                short8 v = {0, 0, 0, 0, 0, 0, 0, 0};
#pragma unroll
                for (int j = 0; j < 8; ++j) {
                    int k = q * 8 + j;
                    if (k < 9) {
                        int ky = k / 3, kx = k % 3;
                        v[j] = (short)Ds[wm * 100 + (r + ky) * 10 + (c + kx)];
                    }
                }
                ad[mi] = v;
            }
#pragma unroll
            for (int ni = 0; ni < 4; ++ni) {
                short8 bfr = *reinterpret_cast<const short8*>(&wtdc[(q * 256 + ocW + ni * 16 + l15) * 8]);
#pragma unroll
                for (int mi = 0; mi < 4; ++mi)
                    acc[mi][ni] = __builtin_amdgcn_mfma_f32_16x16x32_bf16(ad[mi], bfr, acc[mi][ni], 0, 0, 0);
            }
        }

        int ldso[2]; size_t go[2]; bool gv[2], wvld[2];
#pragma unroll
        for (int it = 0; it < 2; ++it) {
            int f = tid + 512 * it;
            int cell = f >> 2, chn = f & 3;
            int n_l = cell / 100, rem = cell % 100;
            int rr = rem / 10, cc = rem % 10;
            wvld[it] = (f < 800);
            gv[it] = wvld[it] && rr >= 1 && rr <= 8 && cc >= 1 && cc <= 8;
            go[it] = ((size_t)((n0 + n_l) * 64 + (rr - 1) * 8 + (cc - 1))) * 256 + chn * 8;
            ldso[it] = cell * 40 + chn * 8;
        }
        short8 st[2];
#pragma unroll
        for (int it = 0; it < 2; ++it) {
            short8 v = {0, 0, 0, 0, 0, 0, 0, 0};
            if (gv[it]) v = *reinterpret_cast<const short8*>(&zt[go[it]]);
            st[it] = v;
        }
        for (int kc = 0; kc < 8; ++kc) {
            unsigned short* As = (kc & 1) ? As1 : As0;
#pragma unroll
            for (int it = 0; it < 2; ++it)
                if (wvld[it]) *reinterpret_cast<short8*>(&As[ldso[it]]) = st[it];
            if (kc < 7) {
#pragma unroll
                for (int it = 0; it < 2; ++it) {
                    short8 v = {0, 0, 0, 0, 0, 0, 0, 0};
                    if (gv[it]) v = *reinterpret_cast<const short8*>(&zt[go[it] + (kc + 1) * 32]);
                    st[it] = v;
                }
            }
            barrier_lgkm();
            if (act) {
#pragma unroll
                for (int tap = 0; tap < 9; ++tap) {
                    const int ky = tap / 3, kx = tap % 3;
                    short8 a[4];
#pragma unroll
                    for (int mi = 0; mi < 4; ++mi) {
                        int pos = mi * 16 + l15;
                        int r = (pos >> 3) + ky, c = (pos & 7) + kx;
                        a[mi] = *reinterpret_cast<const short8*>(&As[(wm * 100 + r * 10 + c) * 40 + q * 8]);
                    }
                    const unsigned short* wb = wtc + (size_t)(((tap * 8 + kc) * 4 + q) * 256) * 8;
#pragma unroll
                    for (int ni = 0; ni < 4; ++ni) {
                        short8 bfr = *reinterpret_cast<const short8*>(&wb[(ocW + ni * 16 + l15) * 8]);
#pragma unroll
                        for (int mi = 0; mi < 4; ++mi)
                            acc[mi][ni] = __builtin_amdgcn_mfma_f32_16x16x32_bf16(a[mi], bfr, acc[mi][ni], 0, 0, 0);
                    }
                }
            }
        }

        if (act) {
#pragma unroll
            for (int ni = 0; ni < 4; ++ni) {
                float s = 0.f, qq = 0.f;
#pragma unroll
                for (int mi = 0; mi < 4; ++mi)
#pragma unroll
                    for (int e = 0; e < 4; ++e) {
                        float v = acc[mi][ni][e];
                        s += v; qq = fmaf(v, v, qq);
                    }
                s += __shfl_xor(s, 16); s += __shfl_xor(s, 32);
                qq += __shfl_xor(qq, 16); qq += __shfl_xor(qq, 32);
                if (lane < 16) {
                    atomicAdd(&sums[0 + ocW + ni * 16 + l15], s);
                    atomicAdd(&sums[256 + ocW + ni * 16 + l15], qq);
                }
            }
        }

        __syncthreads();
        if (act) {
            float* T = Ts + w * 1088;
#pragma unroll
            for (int mi = 0; mi < 4; ++mi) {
#pragma unroll
                for (int ni = 0; ni < 4; ++ni)
#pragma unroll
                    for (int e = 0; e < 4; ++e)
                        T[(ni * 16 + l15) * 17 + q * 4 + e] = acc[mi][ni][e];
#pragma unroll
                for (int eo = 0; eo < 16; ++eo) {
                    int ocl = eo * 4 + q;
                    float v = T[ocl * 17 + l15];
                    y_cls[(size_t)(n0 + wm) * 16384 + (size_t)(ocW + ocl) * 64 + mi * 16 + l15] = f2bf(v);
                }
            }
        }
    }
}

// ---------------------------------------------------------------- lin (lin_reg2 + lin_cls merged, BN folded)
__global__ __launch_bounds__(256) void k_lin(
    const unsigned short* __restrict__ y_reg, const unsigned short* __restrict__ y_cls,
    const float* __restrict__ sums,
    const float* __restrict__ g_cls, const float* __restrict__ b_cls,
    const float* __restrict__ g_reg, const float* __restrict__ b_reg,
    const float* __restrict__ w_reg, const float* __restrict__ w_cls,
    float* __restrict__ part, float* __restrict__ out_cls) {
    __shared__ __align__(16) char smem[35328];
    const int tid = threadIdx.x;
    const int wv = tid >> 6, lane = tid & 63;
    const int l15 = lane & 15, q = lane >> 4;

    if (blockIdx.x < 512) {
        // ================= lin_reg2 =================
        unsigned short* A_l = (unsigned short*)smem;         // 32*520 ushorts
        float* ss_l = (float*)(smem + 33280);                // 512 f32
        {
            float mean = sums[512 + tid] * (1.f / 65536.f);
            float var = sums[768 + tid] * (1.f / 65536.f) - mean * mean;
            float sc = g_reg[tid] * rsqrtf(var + 1e-5f);
            ss_l[tid] = sc;
            ss_l[256 + tid] = b_reg[tid] - mean * sc;
        }
        const int k0 = blockIdx.x * 512;
        const int jw = wv * 80;

        f32x4 acc[5][4];
#pragma unroll
        for (int ni = 0; ni < 5; ++ni)
#pragma unroll
            for (int mi = 0; mi < 4; ++mi) acc[ni][mi] = (f32x4){0.f, 0.f, 0.f, 0.f};

        for (int scn = 0; scn < 2; ++scn) {
            const int ksub = k0 + scn * 256;
            const int ch = ksub >> 10;
            // issue W loads for kk=0 BEFORE the A-stage (hidden under stage latency)
            float4 w0[5], w1[5];
#pragma unroll
            for (int ni = 0; ni < 5; ++ni) {
                const float* wp = &w_reg[(size_t)(jw + ni * 16 + l15) * 262144 + ksub + q * 8];
                w0[ni] = *reinterpret_cast<const float4*>(wp);
                w1[ni] = *reinterpret_cast<const float4*>(wp + 4);
            }
            barrier_lgkm();                     // protects A_l reuse + ss_l visibility; no vmcnt drain
            const float scf = ss_l[ch], shf = ss_l[256 + ch];
            {
                const int c = tid & 31, nb = tid >> 5;
#pragma unroll
                for (int p = 0; p < 8; ++p) {
                    const int n = p * 8 + nb;
                    short8 v = *reinterpret_cast<const short8*>(&y_reg[(size_t)n * 262144 + ksub + c * 8]);
                    float f[8];
#pragma unroll
                    for (int j = 0; j < 8; ++j)
                        f[j] = fmaxf(fmaf(bf2f((unsigned short)v[j]), scf, shf), 0.f);
                    *reinterpret_cast<short8*>(&A_l[c * 520 + n * 8]) = pack8_trunc(f);
                }
            }
            barrier_lgkm();
#pragma unroll
            for (int kk = 0; kk < 8; ++kk) {
                short8 b[5];
#pragma unroll
                for (int ni = 0; ni < 5; ++ni) {
                    float f[8] = {w0[ni].x, w0[ni].y, w0[ni].z, w0[ni].w,
                                  w1[ni].x, w1[ni].y, w1[ni].z, w1[ni].w};
                    b[ni] = pack8_trunc(f);
                }
                if (kk < 7) {
#pragma unroll
                    for (int ni = 0; ni < 5; ++ni) {
                        const float* wp = &w_reg[(size_t)(jw + ni * 16 + l15) * 262144 + ksub + (kk + 1) * 32 + q * 8];
                        w0[ni] = *reinterpret_cast<const float4*>(wp);
                        w1[ni] = *reinterpret_cast<const float4*>(wp + 4);
                    }
                }
                short8 a[4];
#pragma unroll
                for (int mi = 0; mi < 4; ++mi)
                    a[mi] = *reinterpret_cast<const short8*>(&A_l[(kk * 4 + q) * 520 + (mi * 16 + l15) * 8]);
#pragma unroll
                for (int ni = 0; ni < 5; ++ni)
#pragma unroll
                    for (int mi = 0; mi < 4; ++mi)
                        acc[ni][mi] = __builtin_amdgcn_mfma_f32_16x16x32_bf16(a[mi], b[ni], acc[ni][mi], 0, 0, 0);
            }
        }

        float* pb = part + (size_t)blockIdx.x * 20480;
#pragma unroll
        for (int ni = 0; ni < 5; ++ni) {
            const int j = jw + ni * 16 + l15;
#pragma unroll
            for (int mi = 0; mi < 4; ++mi)
#pragma unroll
                for (int e = 0; e < 4; ++e) {
                    const int n = mi * 16 + q * 4 + e;
                    pb[n * 320 + j] = acc[ni][mi][e];
                }
        }
    } else {
        // ================= lin_cls =================
        float* ss_l = (float*)smem;
        {
            float mean = sums[tid] * (1.f / 4096.f);
            float var = sums[256 + tid] * (1.f / 4096.f) - mean * mean;
            float sc = g_cls[tid] * rsqrtf(var + 1e-5f);
            ss_l[tid] = sc;
            ss_l[256 + tid] = b_cls[tid] - mean * sc;
        }
        __syncthreads();
        const int kb = (blockIdx.x - 512) * 256;
        const int q4 = q;
        f32x4 acc[5];
#pragma unroll
        for (int ni = 0; ni < 5; ++ni) acc[ni] = (f32x4){0.f, 0.f, 0.f, 0.f};
#pragma unroll
        for (int ks = 0; ks < 8; ++ks) {
            const int kx = kb + ks * 32 + q4 * 8;
            short8 yv = *reinterpret_cast<const short8*>(&y_cls[(wv * 16 + l15) * 16384 + kx]);
            const int ch = kx >> 6;
            const float sc = ss_l[ch], sh = ss_l[256 + ch];
            float f[8];
#pragma unroll
            for (int j = 0; j < 8; ++j) f[j] = fmaxf(fmaf(bf2f((unsigned short)yv[j]), sc, sh), 0.f);
            short8 a = pack8_trunc(f);
#pragma unroll
            for (int ni = 0; ni < 5; ++ni) {
                const float* wp = &w_cls[(size_t)(ni * 16 + l15) * 16384 + kx];
                float4 b0 = *reinterpret_cast<const float4*>(wp);
                float4 b1 = *reinterpret_cast<const float4*>(wp + 4);
                float g[8] = {b0.x, b0.y, b0.z, b0.w, b1.x, b1.y, b1.z, b1.w};
                acc[ni] = __builtin_amdgcn_mfma_f32_16x16x32_bf16(a, pack8_trunc(g), acc[ni], 0, 0, 0);
            }
        }
#pragma unroll
        for (int ni = 0; ni < 5; ++ni)
#pragma unroll
            for (int e = 0; e < 4; ++e)
                atomicAdd(&out_cls[(wv * 16 + q4 * 4 + e) * 80 + ni * 16 + l15], acc[ni][e]);
    }
}

// reduce: out[n][j] (+= bias, pre-seeded) over 512 partial blocks; grid (80, 8)
__global__ __launch_bounds__(256) void k_lin_red(const float* __restrict__ part, float* __restrict__ out_loc) {
    const int idx = blockIdx.x * 256 + threadIdx.x;
    const int b0 = blockIdx.y * 64;
    float s0 = 0.f, s1 = 0.f, s2 = 0.f, s3 = 0.f;
#pragma unroll 4
    for (int b = 0; b < 64; b += 4) {
        s0 += part[(size_t)(b0 + b + 0) * 20480 + idx];
        s1 += part[(size_t)(b0 + b + 1) * 20480 + idx];
        s2 += part[(size_t)(b0 + b + 2) * 20480 + idx];
        s3 += part[(size_t)(b0 + b + 3) * 20480 + idx];
    }
    atomicAdd(&out_loc[idx], (s0 + s1) + (s2 + s3));
}

// ---------------------------------------------------------------- launch
extern "C" void kernel_launch(void* const* d_in, const int* in_sizes, int n_in,
                              void* d_out, int out_size, void* d_ws, size_t ws_size,
                              hipStream_t stream) {
    const float* z_f        = (const float*)d_in[0];
    const float* x_f        = (const float*)d_in[1];
    const float* conv_cls_w = (const float*)d_in[2];
    const float* bn_cls_g   = (const float*)d_in[3];
    const float* bn_cls_b   = (const float*)d_in[4];
    const float* conv_reg_w = (const float*)d_in[5];
    const float* bn_reg_g   = (const float*)d_in[6];
    const float* bn_reg_b   = (const float*)d_in[7];
    const float* lin_cls_w  = (const float*)d_in[8];
    const float* lin_cls_b  = (const float*)d_in[9];
    const float* lin_reg_w  = (const float*)d_in[10];
    const float* lin_reg_b  = (const float*)d_in[11];

    float* out = (float*)d_out;
    float* ws  = (float*)d_ws;
    unsigned* ds_enc = (unsigned*)(ws + WS_DS_ENC);
    float* dist_t = ws + WS_DT;
    float* sums   = ws + WS_SUMS;
    unsigned short* y_cls = (unsigned short*)(ws + WS_YCLS);
    unsigned short* y_reg = (unsigned short*)(ws + WS_YREG);
    unsigned short* xt    = (unsigned short*)(ws + WS_XT);
    unsigned short* zt    = (unsigned short*)(ws + WS_ZT);
    unsigned short* wtr   = (unsigned short*)(ws + WS_WTR);
    unsigned short* wtdr  = (unsigned short*)(ws + WS_WTDR);
    unsigned short* wtc   = (unsigned short*)(ws + WS_WTC);
    unsigned short* wtdc  = (unsigned short*)(ws + WS_WTDC);
    float* part   = ws + WS_PART;
    float* xsq    = ws + WS_XSQ;
    float* zsq    = ws + WS_ZSQ;

    hipLaunchKernelGGL(k_prep, dim3(2776), dim3(256), 0, stream,
                       x_f, z_f, conv_reg_w, conv_cls_w, xt, zt, xsq, zsq,
                       wtr, wtdr, wtc, wtdc, ds_enc, sums, out, out + 5120, lin_cls_b, lin_reg_b);
    hipLaunchKernelGGL(k_dist, dim3(4, 64), dim3(256), 0, stream, zt, xt, zsq, xsq, dist_t, ds_enc);
    hipLaunchKernelGGL(k_conv, dim3(576), dim3(512), 0, stream,
                       xt, dist_t, zt, ds_enc, wtr, wtdr, wtc, wtdc, y_reg, y_cls, sums);
    hipLaunchKernelGGL(k_lin, dim3(576), dim3(256), 0, stream,
                       y_reg, y_cls, sums, bn_cls_g, bn_cls_b, bn_reg_g, bn_reg_b,
                       lin_reg_w, lin_cls_w, part, out);
    hipLaunchKernelGGL(k_lin_red, dim3(80, 8), dim3(256), 0, stream, part, out + 5120);
}